// Round 3
// baseline (737.610 us; speedup 1.0000x reference)
//
#include <hip/hip_runtime.h>
#include <hip/hip_bf16.h>
#include <math.h>

// ---------------- problem constants ----------------
#define N_NODES 10000
#define N_EDGES0 160000
#define E_TOT (N_EDGES0 + N_NODES)   // + self loops
#define H1 4
#define C1 512
#define F1 2048                      // H1*C1
#define IN_DIM 768
#define C2 768
#define NEG_SLOPE 0.2f

typedef _Float16 f16x8 __attribute__((ext_vector_type(8)));
typedef _Float16 f16x4 __attribute__((ext_vector_type(4)));
typedef float f32x4 __attribute__((ext_vector_type(4)));

typedef __attribute__((address_space(1))) const void* gas_ptr;
typedef __attribute__((address_space(3))) void* las_ptr;
static __device__ __forceinline__ void gload16(const void* g, void* l) {
  __builtin_amdgcn_global_load_lds((gas_ptr)g, (las_ptr)l, 16, 0, 0);
}

// Monotonic float<->unsigned encoding so atomicMax works for signed floats.
static __device__ __forceinline__ unsigned enc_f(float v) {
  unsigned u = __float_as_uint(v);
  return (u & 0x80000000u) ? ~u : (u | 0x80000000u);
}
static __device__ __forceinline__ float dec_f(unsigned u) {
  return (u & 0x80000000u) ? __uint_as_float(u ^ 0x80000000u)
                           : __uint_as_float(~u);
}

// edge e -> (src, dst); e >= N_EDGES0 are the implicit self-loops
static __device__ __forceinline__ void edge_sd(const int* __restrict__ ei, int e,
                                               int& s, int& d) {
  if (e < N_EDGES0) { s = ei[e]; d = ei[N_EDGES0 + e]; }
  else { s = e - N_EDGES0; d = s; }
}

// ---------------- fp32 -> f16 hi/lo split (elementwise, float4) -------------
__global__ void split_k(const float* __restrict__ in, _Float16* __restrict__ hi,
                        _Float16* __restrict__ lo, int n4) {
  int i = blockIdx.x * blockDim.x + threadIdx.x;
  if (i >= n4) return;
  float4 v = ((const float4*)in)[i];
  f16x4 h, l;
  h.x = (_Float16)v.x; l.x = (_Float16)(v.x - (float)h.x);
  h.y = (_Float16)v.y; l.y = (_Float16)(v.y - (float)h.y);
  h.z = (_Float16)v.z; l.z = (_Float16)(v.z - (float)h.z);
  h.w = (_Float16)v.w; l.w = (_Float16)(v.w - (float)h.w);
  ((f16x4*)hi)[i] = h;
  ((f16x4*)lo)[i] = l;
}

// ---------------- W [K][N] fp32 -> W^T [N][K] f16 hi/lo ---------------------
__global__ void tsplit_k(const float* __restrict__ W, _Float16* __restrict__ hi,
                         _Float16* __restrict__ lo, int K, int N) {
  __shared__ float tile[32][33];
  const int nb = blockIdx.x * 32, kb = blockIdx.y * 32;
  const int tx = threadIdx.x, ty = threadIdx.y;  // 32 x 8
  for (int r = ty; r < 32; r += 8)
    tile[r][tx] = W[(size_t)(kb + r) * N + nb + tx];
  __syncthreads();
  for (int r = ty; r < 32; r += 8) {
    float v = tile[tx][r];  // = W[kb+tx][nb+r]
    _Float16 h = (_Float16)v;
    hi[(size_t)(nb + r) * K + kb + tx] = h;
    lo[(size_t)(nb + r) * K + kb + tx] = (_Float16)(v - (float)h);
  }
}

// ---------------- split-f16 MFMA GEMM: C[M,N] = A[M,K] @ Bt[N,K]^T ----------
// 128x128 tile, BK=32, 4 waves, each wave 64x64 (4x4 16x16 frags).
// 3 MFMA passes: hi*hi + hi*lo + lo*hi  (~fp32 accuracy).
// Fused epilogue: per-row partial dot with a_src/a_dst -> atomicAdd to als/ald.
__global__ __launch_bounds__(256) void gemm_sf16(
    const _Float16* __restrict__ Ahi, const _Float16* __restrict__ Alo,
    const _Float16* __restrict__ Bhi, const _Float16* __restrict__ Blo,
    float* __restrict__ C, int M, int N, int K,
    const float* __restrict__ asrc, const float* __restrict__ adst,
    float* __restrict__ als, float* __restrict__ ald, int Hh, int Cdim) {
  __shared__ _Float16 sAh[128 * 32];
  __shared__ _Float16 sAl[128 * 32];
  __shared__ _Float16 sBh[128 * 32];
  __shared__ _Float16 sBl[128 * 32];

  const int t = threadIdx.x;
  const int w = t >> 6, lane = t & 63;
  const int m0 = blockIdx.y * 128, n0 = blockIdx.x * 128;

  // staging decomposition: chunk i covers LDS bytes [w*1024 + i*4096, +1024)
  const int o0 = w * 1024 + lane * 16;
  const int o1 = o0 + 4096;
  const int ma0 = o0 >> 6, cb0 = o0 & 63;  // row, byte-in-row (64B rows)
  const int ma1 = o1 >> 6, cb1 = o1 & 63;
  const int rA0 = min(m0 + ma0, M - 1), rA1 = min(m0 + ma1, M - 1);
  const size_t gA0 = (size_t)rA0 * K + (cb0 >> 1);
  const size_t gA1 = (size_t)rA1 * K + (cb1 >> 1);
  const size_t gB0 = (size_t)(n0 + ma0) * K + (cb0 >> 1);
  const size_t gB1 = (size_t)(n0 + ma1) * K + (cb1 >> 1);

  char* lA0 = (char*)sAh + w * 1024;           // wave-uniform LDS bases
  char* lA1 = lA0 + 4096;
  char* lAl0 = (char*)sAl + w * 1024;
  char* lAl1 = lAl0 + 4096;
  char* lB0 = (char*)sBh + w * 1024;
  char* lB1 = lB0 + 4096;
  char* lBl0 = (char*)sBl + w * 1024;
  char* lBl1 = lBl0 + 4096;

  // fragment read offsets (f16 elements)
  const int wr = w >> 1, wc = w & 1;
  const int lr = lane & 15, lg = lane >> 4;
  const int aoff = (wr * 64 + lr) * 32 + lg * 8;
  const int boff = (wc * 64 + lr) * 32 + lg * 8;

  f32x4 acc[4][4];
#pragma unroll
  for (int i = 0; i < 4; i++)
#pragma unroll
    for (int j = 0; j < 4; j++) acc[i][j] = (f32x4)(0.f);

  for (int k0 = 0; k0 < K; k0 += 32) {
    __syncthreads();  // previous iter's ds_reads done before overwrite
    gload16(Ahi + gA0 + k0, lA0);
    gload16(Ahi + gA1 + k0, lA1);
    gload16(Alo + gA0 + k0, lAl0);
    gload16(Alo + gA1 + k0, lAl1);
    gload16(Bhi + gB0 + k0, lB0);
    gload16(Bhi + gB1 + k0, lB1);
    gload16(Blo + gB0 + k0, lBl0);
    gload16(Blo + gB1 + k0, lBl1);
    __syncthreads();  // barrier drains vmcnt -> tiles ready

    f16x8 ah[4], al[4], bh[4], bl[4];
#pragma unroll
    for (int i = 0; i < 4; i++) {
      ah[i] = *(const f16x8*)&sAh[aoff + i * 16 * 32];
      al[i] = *(const f16x8*)&sAl[aoff + i * 16 * 32];
      bh[i] = *(const f16x8*)&sBh[boff + i * 16 * 32];
      bl[i] = *(const f16x8*)&sBl[boff + i * 16 * 32];
    }
#pragma unroll
    for (int i = 0; i < 4; i++)
#pragma unroll
      for (int j = 0; j < 4; j++) {
        acc[i][j] = __builtin_amdgcn_mfma_f32_16x16x32_f16(ah[i], bh[j], acc[i][j], 0, 0, 0);
        acc[i][j] = __builtin_amdgcn_mfma_f32_16x16x32_f16(ah[i], bl[j], acc[i][j], 0, 0, 0);
        acc[i][j] = __builtin_amdgcn_mfma_f32_16x16x32_f16(al[i], bh[j], acc[i][j], 0, 0, 0);
      }
  }

  // C/D layout: col = lane&15, row = (lane>>4)*4 + reg  [m89/m91 verified]
#pragma unroll
  for (int i = 0; i < 4; i++)
#pragma unroll
    for (int j = 0; j < 4; j++) {
      const int col = n0 + wc * 64 + j * 16 + lr;
      const int rbase = m0 + wr * 64 + i * 16 + lg * 4;
#pragma unroll
      for (int r = 0; r < 4; r++) {
        int row = rbase + r;
        if (row < M) C[(size_t)row * N + col] = acc[i][j][r];
      }
    }

  // fused attention logits: per-row partial <h_row_slice, a_src/a_dst slice>.
  // 128-col tile lies in a single head (Cdim % 128 == 0, n0 aligned).
  const int head = n0 / Cdim;
  const int cbase = n0 - head * Cdim + wc * 64 + lr;
  float asv[4], adv[4];
#pragma unroll
  for (int j = 0; j < 4; j++) {
    asv[j] = asrc[(size_t)head * Cdim + cbase + j * 16];
    adv[j] = adst[(size_t)head * Cdim + cbase + j * 16];
  }
#pragma unroll
  for (int i = 0; i < 4; i++) {
    const int rbase = m0 + wr * 64 + i * 16 + lg * 4;
#pragma unroll
    for (int r = 0; r < 4; r++) {
      float ss = 0.f, sd = 0.f;
#pragma unroll
      for (int j = 0; j < 4; j++) {
        float v = acc[i][j][r];
        ss = fmaf(v, asv[j], ss);
        sd = fmaf(v, adv[j], sd);
      }
#pragma unroll
      for (int o = 8; o; o >>= 1) {  // reduce across lr (16-lane group)
        ss += __shfl_xor(ss, o);
        sd += __shfl_xor(sd, o);
      }
      if (lr == 0 && rbase + r < M) {
        atomicAdd(&als[(size_t)(rbase + r) * Hh + head], ss);
        atomicAdd(&ald[(size_t)(rbase + r) * Hh + head], sd);
      }
    }
  }
}

// ---------------- edge softmax passes ----------------
__global__ void edge_max_k(const int* __restrict__ ei,
                           const float* __restrict__ als,
                           const float* __restrict__ ald,
                           float* __restrict__ ev, unsigned* __restrict__ menc,
                           int Hh) {
  int idx = blockIdx.x * blockDim.x + threadIdx.x;
  if (idx >= E_TOT * Hh) return;
  int e = idx / Hh, hh = idx - e * Hh;
  int s, d; edge_sd(ei, e, s, d);
  float x = als[s * Hh + hh] + ald[d * Hh + hh];
  float v = x > 0.f ? x : NEG_SLOPE * x;   // leaky_relu
  ev[idx] = v;
  atomicMax(&menc[d * Hh + hh], enc_f(v));
}

// writes exp values directly in CSR (dst-sorted) order -> contiguous reads in agg
__global__ void edge_exp_k(const int* __restrict__ ei,
                           const unsigned* __restrict__ menc,
                           const float* __restrict__ ev,
                           const int* __restrict__ csr_pos,
                           float* __restrict__ evs, float* __restrict__ denom,
                           int Hh) {
  int idx = blockIdx.x * blockDim.x + threadIdx.x;
  if (idx >= E_TOT * Hh) return;
  int e = idx / Hh, hh = idx - e * Hh;
  int s, d; edge_sd(ei, e, s, d);
  float m = dec_f(menc[d * Hh + hh]);
  float ex = expf(ev[idx] - m);
  evs[(size_t)csr_pos[e] * Hh + hh] = ex;
  atomicAdd(&denom[d * Hh + hh], ex);
}

// ---------------- CSR build (dst-sorted) ----------------
__global__ void hist_k(const int* __restrict__ ei, int* __restrict__ count) {
  int e = blockIdx.x * blockDim.x + threadIdx.x;
  if (e >= E_TOT) return;
  int s, d; edge_sd(ei, e, s, d);
  atomicAdd(&count[d], 1);
}

__global__ __launch_bounds__(1024) void scan_k(const int* __restrict__ count,
                                               int* __restrict__ rowstart,
                                               int N, int total) {
  __shared__ int sums[1024];
  __shared__ int carry_s;
  int t = threadIdx.x;
  if (t == 0) carry_s = 0;
  __syncthreads();
  for (int base = 0; base < N; base += 1024) {
    int i = base + t;
    int c = (i < N) ? count[i] : 0;
    sums[t] = c;
    __syncthreads();
    for (int off = 1; off < 1024; off <<= 1) {
      int v = (t >= off) ? sums[t - off] : 0;
      __syncthreads();
      sums[t] += v;
      __syncthreads();
    }
    int carry = carry_s;
    if (i < N) rowstart[i] = carry + sums[t] - c;  // exclusive
    __syncthreads();
    if (t == 1023) carry_s = carry + sums[1023];
    __syncthreads();
  }
  if (t == 0) rowstart[N] = total;
}

__global__ void scatter_k(const int* __restrict__ ei,
                          const int* __restrict__ rowstart,
                          int* __restrict__ cursor,
                          int* __restrict__ csr_src, int* __restrict__ csr_pos) {
  int e = blockIdx.x * blockDim.x + threadIdx.x;
  if (e >= E_TOT) return;
  int s, d; edge_sd(ei, e, s, d);
  int pos = rowstart[d] + atomicAdd(&cursor[d], 1);
  csr_src[pos] = s;
  csr_pos[e] = pos;   // inverse permutation (edge -> CSR slot)
}

// ---------------- aggregation: out[n,:] = (sum_in ev * h[src,:]) / denom ----
// Unrolled edge loop: batch src/weight loads, then UN*FT/4 independent float4
// gathers in flight (latency hiding). Normalize once at the end.
template <int FT, bool ELU, bool SPLIT>
__global__ __launch_bounds__(256) void aggregate_k(
    const float* __restrict__ hsrc, const float* __restrict__ evs,
    const float* __restrict__ denom, const float* __restrict__ bias,
    const int* __restrict__ rowstart, const int* __restrict__ csr_src,
    float* __restrict__ out,
    _Float16* __restrict__ ohi, _Float16* __restrict__ olo,
    int Hh, int C) {
  const int n = blockIdx.x;
  const int t = threadIdx.x;
  const int F = Hh * C;
  const int f0 = t * FT;
  const int hh = f0 / C;                       // FT divides C -> no straddle
  const float inv = 1.f / (denom[n * Hh + hh] + 1e-16f);
  float acc[FT];
#pragma unroll
  for (int i = 0; i < FT; i++) acc[i] = 0.f;
  const int j0 = rowstart[n], j1 = rowstart[n + 1];

  constexpr int UN = (FT == 8) ? 4 : 8;
  int j = j0;
  for (; j + UN <= j1; j += UN) {
    int   sidx[UN];
    float wv[UN];
#pragma unroll
    for (int u = 0; u < UN; u++) sidx[u] = csr_src[j + u];
#pragma unroll
    for (int u = 0; u < UN; u++) wv[u] = evs[(size_t)(j + u) * Hh + hh];
    float4 va[UN][FT / 4];
#pragma unroll
    for (int u = 0; u < UN; u++) {
      const float* hp = hsrc + (size_t)sidx[u] * F + f0;
#pragma unroll
      for (int q = 0; q < FT / 4; q++) va[u][q] = *(const float4*)(hp + q * 4);
    }
#pragma unroll
    for (int u = 0; u < UN; u++)
#pragma unroll
      for (int q = 0; q < FT / 4; q++) {
        acc[q * 4 + 0] = fmaf(wv[u], va[u][q].x, acc[q * 4 + 0]);
        acc[q * 4 + 1] = fmaf(wv[u], va[u][q].y, acc[q * 4 + 1]);
        acc[q * 4 + 2] = fmaf(wv[u], va[u][q].z, acc[q * 4 + 2]);
        acc[q * 4 + 3] = fmaf(wv[u], va[u][q].w, acc[q * 4 + 3]);
      }
  }
  for (; j < j1; j++) {
    int s = csr_src[j];
    float wgt = evs[(size_t)j * Hh + hh];
    const float* hp = hsrc + (size_t)s * F + f0;
#pragma unroll
    for (int q = 0; q < FT / 4; q++) {
      float4 v = *(const float4*)(hp + q * 4);
      acc[q * 4 + 0] = fmaf(wgt, v.x, acc[q * 4 + 0]);
      acc[q * 4 + 1] = fmaf(wgt, v.y, acc[q * 4 + 1]);
      acc[q * 4 + 2] = fmaf(wgt, v.z, acc[q * 4 + 2]);
      acc[q * 4 + 3] = fmaf(wgt, v.w, acc[q * 4 + 3]);
    }
  }

  if (SPLIT) {
    f16x8 h, l;
#pragma unroll
    for (int i = 0; i < FT; i++) {
      float o = acc[i] * inv + bias[f0 + i];
      if (ELU) o = o > 0.f ? o : expm1f(o);
      _Float16 hv = (_Float16)o;
      h[i & 7] = hv;
      l[i & 7] = (_Float16)(o - (float)hv);
    }
    *(f16x8*)&ohi[(size_t)n * F + f0] = h;
    *(f16x8*)&olo[(size_t)n * F + f0] = l;
  } else {
#pragma unroll
    for (int i = 0; i < FT; i++) {
      float o = acc[i] * inv + bias[f0 + i];
      if (ELU) o = o > 0.f ? o : expm1f(o);
      out[(size_t)n * F + f0 + i] = o;
    }
  }
}

// ---------------- launch ----------------
extern "C" void kernel_launch(void* const* d_in, const int* in_sizes, int n_in,
                              void* d_out, int out_size, void* d_ws, size_t ws_size,
                              hipStream_t stream) {
  const float* x   = (const float*)d_in[0];
  const int*   ei  = (const int*)d_in[1];   // [2, 160000]; JAX x64 off -> int32
  const float* W1  = (const float*)d_in[2];
  const float* as1 = (const float*)d_in[3];
  const float* ad1 = (const float*)d_in[4];
  const float* b1  = (const float*)d_in[5];
  const float* W2  = (const float*)d_in[6];
  const float* as2 = (const float*)d_in[7];
  const float* ad2 = (const float*)d_in[8];
  const float* b2  = (const float*)d_in[9];
  float* out = (float*)d_out;

  // bump allocator on workspace (everything rebuilt every call; ws is poisoned)
  char* p = (char*)d_ws;
  auto alloc = [&](size_t bytes) {
    char* r = p;
    p += (bytes + 255) & ~(size_t)255;
    return r;
  };
  float*     h1    = (float*)alloc((size_t)N_NODES * F1 * 4);      // 81.9 MB
  _Float16*  xhi   = (_Float16*)alloc((size_t)N_NODES * IN_DIM * 2);
  _Float16*  xlo   = (_Float16*)alloc((size_t)N_NODES * IN_DIM * 2);
  _Float16*  W1hi  = (_Float16*)alloc((size_t)IN_DIM * F1 * 2);    // [F1][IN_DIM]
  _Float16*  W1lo  = (_Float16*)alloc((size_t)IN_DIM * F1 * 2);
  _Float16*  W2hi  = (_Float16*)alloc((size_t)F1 * C2 * 2);        // [C2][F1]
  _Float16*  W2lo  = (_Float16*)alloc((size_t)F1 * C2 * 2);
  _Float16*  h2hi  = (_Float16*)alloc((size_t)N_NODES * F1 * 2);   // 41 MB
  _Float16*  h2lo  = (_Float16*)alloc((size_t)N_NODES * F1 * 2);
  float*     als   = (float*)alloc((size_t)N_NODES * H1 * 4);
  float*     ald   = (float*)alloc((size_t)N_NODES * H1 * 4);
  unsigned*  menc  = (unsigned*)alloc((size_t)N_NODES * H1 * 4);
  float*     denom = (float*)alloc((size_t)N_NODES * H1 * 4);
  float*     ev    = (float*)alloc((size_t)E_TOT * H1 * 4);
  float*     evs   = (float*)alloc((size_t)E_TOT * H1 * 4);
  int*       count    = (int*)alloc((size_t)N_NODES * 4);
  int*       rowstart = (int*)alloc((size_t)(N_NODES + 1) * 4);
  int*       cursor   = (int*)alloc((size_t)N_NODES * 4);
  int*       csr_src  = (int*)alloc((size_t)E_TOT * 4);
  int*       csr_pos  = (int*)alloc((size_t)E_TOT * 4);
  float*     h3 = h1;  // h1 dead after layer-1 aggregation; alias for GEMM2 out

  const int EB = (E_TOT + 255) / 256;

  // CSR by destination (same graph both layers)
  hipMemsetAsync(count, 0, (size_t)N_NODES * 4, stream);
  hipMemsetAsync(cursor, 0, (size_t)N_NODES * 4, stream);
  hist_k<<<EB, 256, 0, stream>>>(ei, count);
  scan_k<<<1, 1024, 0, stream>>>(count, rowstart, N_NODES, E_TOT);
  scatter_k<<<EB, 256, 0, stream>>>(ei, rowstart, cursor, csr_src, csr_pos);

  // input conversions
  split_k<<<(N_NODES * IN_DIM / 4 + 255) / 256, 256, 0, stream>>>(x, xhi, xlo,
                                                                  N_NODES * IN_DIM / 4);
  tsplit_k<<<dim3(F1 / 32, IN_DIM / 32), dim3(32, 8), 0, stream>>>(W1, W1hi, W1lo,
                                                                   IN_DIM, F1);
  tsplit_k<<<dim3(C2 / 32, F1 / 32), dim3(32, 8), 0, stream>>>(W2, W2hi, W2lo,
                                                               F1, C2);

  // ---- layer 1 ----
  hipMemsetAsync(als, 0, (size_t)N_NODES * H1 * 4, stream);
  hipMemsetAsync(ald, 0, (size_t)N_NODES * H1 * 4, stream);
  gemm_sf16<<<dim3(F1 / 128, (N_NODES + 127) / 128), 256, 0, stream>>>(
      xhi, xlo, W1hi, W1lo, h1, N_NODES, F1, IN_DIM,
      as1, ad1, als, ald, H1, C1);
  hipMemsetAsync(menc, 0, (size_t)N_NODES * H1 * 4, stream);
  hipMemsetAsync(denom, 0, (size_t)N_NODES * H1 * 4, stream);
  edge_max_k<<<(E_TOT * H1 + 255) / 256, 256, 0, stream>>>(ei, als, ald, ev, menc, H1);
  edge_exp_k<<<(E_TOT * H1 + 255) / 256, 256, 0, stream>>>(ei, menc, ev, csr_pos,
                                                           evs, denom, H1);
  aggregate_k<8, true, true><<<N_NODES, 256, 0, stream>>>(
      h1, evs, denom, b1, rowstart, csr_src, nullptr, h2hi, h2lo, H1, C1);

  // ---- layer 2 ----
  hipMemsetAsync(als, 0, (size_t)N_NODES * 4, stream);
  hipMemsetAsync(ald, 0, (size_t)N_NODES * 4, stream);
  gemm_sf16<<<dim3(C2 / 128, (N_NODES + 127) / 128), 256, 0, stream>>>(
      h2hi, h2lo, W2hi, W2lo, h3, N_NODES, C2, F1,
      as2, ad2, als, ald, 1, C2);
  hipMemsetAsync(menc, 0, (size_t)N_NODES * 4, stream);
  hipMemsetAsync(denom, 0, (size_t)N_NODES * 4, stream);
  edge_max_k<<<EB, 256, 0, stream>>>(ei, als, ald, ev, menc, 1);
  edge_exp_k<<<EB, 256, 0, stream>>>(ei, menc, ev, csr_pos, evs, denom, 1);
  aggregate_k<4, false, false><<<N_NODES, 192, 0, stream>>>(
      h3, evs, denom, b2, rowstart, csr_src, out, nullptr, nullptr, 1, C2);
}

// Round 4
// 640.556 us; speedup vs baseline: 1.1515x; 1.1515x over previous
//
#include <hip/hip_runtime.h>
#include <hip/hip_bf16.h>
#include <math.h>

// ---------------- problem constants ----------------
#define N_NODES 10000
#define N_EDGES0 160000
#define E_TOT (N_EDGES0 + N_NODES)   // + self loops
#define H1 4
#define C1 512
#define F1 2048                      // H1*C1
#define IN_DIM 768
#define C2 768
#define NEG_SLOPE 0.2f

typedef _Float16 f16x8 __attribute__((ext_vector_type(8)));
typedef _Float16 f16x4 __attribute__((ext_vector_type(4)));
typedef float f32x4 __attribute__((ext_vector_type(4)));

typedef __attribute__((address_space(1))) const void* gas_ptr;
typedef __attribute__((address_space(3))) void* las_ptr;
static __device__ __forceinline__ void gload16(const void* g, void* l) {
  __builtin_amdgcn_global_load_lds((gas_ptr)g, (las_ptr)l, 16, 0, 0);
}

// Monotonic float<->unsigned encoding so atomicMax works for signed floats.
static __device__ __forceinline__ unsigned enc_f(float v) {
  unsigned u = __float_as_uint(v);
  return (u & 0x80000000u) ? ~u : (u | 0x80000000u);
}
static __device__ __forceinline__ float dec_f(unsigned u) {
  return (u & 0x80000000u) ? __uint_as_float(u ^ 0x80000000u)
                           : __uint_as_float(~u);
}

// edge e -> (src, dst); e >= N_EDGES0 are the implicit self-loops
static __device__ __forceinline__ void edge_sd(const int* __restrict__ ei, int e,
                                               int& s, int& d) {
  if (e < N_EDGES0) { s = ei[e]; d = ei[N_EDGES0 + e]; }
  else { s = e - N_EDGES0; d = s; }
}

// ---------------- W [K][N] fp32 -> W^T [N][K] f16 hi/lo ---------------------
__global__ void tsplit_k(const float* __restrict__ W, _Float16* __restrict__ hi,
                         _Float16* __restrict__ lo, int K, int N) {
  __shared__ float tile[32][33];
  const int nb = blockIdx.x * 32, kb = blockIdx.y * 32;
  const int tx = threadIdx.x, ty = threadIdx.y;  // 32 x 8
  for (int r = ty; r < 32; r += 8)
    tile[r][tx] = W[(size_t)(kb + r) * N + nb + tx];
  __syncthreads();
  for (int r = ty; r < 32; r += 8) {
    float v = tile[tx][r];  // = W[kb+tx][nb+r]
    _Float16 h = (_Float16)v;
    hi[(size_t)(nb + r) * K + kb + tx] = h;
    lo[(size_t)(nb + r) * K + kb + tx] = (_Float16)(v - (float)h);
  }
}

// ---- layer-1 attn vectors projected into x-space: ws[h,k] = sum_c W1[k,h*C1+c]*a[h,c]
__global__ void proj_attn_k(const float* __restrict__ W1,
                            const float* __restrict__ as1,
                            const float* __restrict__ ad1,
                            float* __restrict__ ws, float* __restrict__ wd) {
  int wv = (blockIdx.x * blockDim.x + threadIdx.x) >> 6;
  int lane = threadIdx.x & 63;
  if (wv >= H1 * IN_DIM) return;
  int h = wv / IN_DIM, k = wv - h * IN_DIM;
  const float* wrow = W1 + (size_t)k * F1 + h * C1;
  const float* sa = as1 + h * C1;
  const float* da = ad1 + h * C1;
  float ss = 0.f, sd = 0.f;
  for (int c = lane; c < C1; c += 64) {
    float v = wrow[c];
    ss = fmaf(v, sa[c], ss);
    sd = fmaf(v, da[c], sd);
  }
#pragma unroll
  for (int o = 32; o; o >>= 1) { ss += __shfl_xor(ss, o); sd += __shfl_xor(sd, o); }
  if (lane == 0) { ws[(size_t)h * IN_DIM + k] = ss; wd[(size_t)h * IN_DIM + k] = sd; }
}

// ---- layer-1 logits from raw x: als[n,h] = x[n,:] . ws[h,:]
__global__ void logits1_k(const float* __restrict__ x,
                          const float* __restrict__ ws, const float* __restrict__ wd,
                          float* __restrict__ als, float* __restrict__ ald) {
  int n = (blockIdx.x * blockDim.x + threadIdx.x) >> 6;
  int lane = threadIdx.x & 63;
  if (n >= N_NODES) return;
  const float* xp = x + (size_t)n * IN_DIM;
  float ss[H1] = {0.f, 0.f, 0.f, 0.f}, sd[H1] = {0.f, 0.f, 0.f, 0.f};
  for (int k = lane; k < IN_DIM; k += 64) {
    float xv = xp[k];
#pragma unroll
    for (int h = 0; h < H1; h++) {
      ss[h] = fmaf(xv, ws[h * IN_DIM + k], ss[h]);
      sd[h] = fmaf(xv, wd[h * IN_DIM + k], sd[h]);
    }
  }
#pragma unroll
  for (int h = 0; h < H1; h++)
#pragma unroll
    for (int o = 32; o; o >>= 1) { ss[h] += __shfl_xor(ss[h], o); sd[h] += __shfl_xor(sd[h], o); }
  if (lane == 0) {
#pragma unroll
    for (int h = 0; h < H1; h++) {
      als[(size_t)n * H1 + h] = ss[h];
      ald[(size_t)n * H1 + h] = sd[h];
    }
  }
}

// ---------------- split-f16 MFMA GEMM: C[M,N] = A[M,K] @ Bt[N,K]^T ----------
// A element (m,k) for output col-tile n0: Ahi[m*lda + (n0/nch)*K + k]
//   (layer 1: per-head xa slices; layer 2: nch huge -> offset 0)
// SPLITOUT=true : epilogue bias+ELU -> f16 hi/lo (ohi/olo), no fp32 C.
// SPLITOUT=false: fp32 C + fused attention logits (atomicAdd als/ald).
template <bool SPLITOUT>
__global__ __launch_bounds__(256) void gemm_sf16(
    const _Float16* __restrict__ Ahi, const _Float16* __restrict__ Alo,
    const _Float16* __restrict__ Bhi, const _Float16* __restrict__ Blo,
    int M, int N, int K, int lda, int nch,
    float* __restrict__ C, const float* __restrict__ bias,
    _Float16* __restrict__ ohi, _Float16* __restrict__ olo,
    const float* __restrict__ asrc, const float* __restrict__ adst,
    float* __restrict__ als, float* __restrict__ ald, int Hh, int Cdim) {
  __shared__ _Float16 sAh[128 * 32];
  __shared__ _Float16 sAl[128 * 32];
  __shared__ _Float16 sBh[128 * 32];
  __shared__ _Float16 sBl[128 * 32];

  const int t = threadIdx.x;
  const int w = t >> 6, lane = t & 63;
  const int m0 = blockIdx.y * 128, n0 = blockIdx.x * 128;
  const size_t hofs = (size_t)(n0 / nch) * K;

  const int o0 = w * 1024 + lane * 16;
  const int o1 = o0 + 4096;
  const int ma0 = o0 >> 6, cb0 = o0 & 63;  // row, byte-in-row (64B rows)
  const int ma1 = o1 >> 6, cb1 = o1 & 63;
  const int rA0 = min(m0 + ma0, M - 1), rA1 = min(m0 + ma1, M - 1);
  const size_t gA0 = (size_t)rA0 * lda + hofs + (cb0 >> 1);
  const size_t gA1 = (size_t)rA1 * lda + hofs + (cb1 >> 1);
  const size_t gB0 = (size_t)(n0 + ma0) * K + (cb0 >> 1);
  const size_t gB1 = (size_t)(n0 + ma1) * K + (cb1 >> 1);

  char* lA0 = (char*)sAh + w * 1024;           // wave-uniform LDS bases
  char* lA1 = lA0 + 4096;
  char* lAl0 = (char*)sAl + w * 1024;
  char* lAl1 = lAl0 + 4096;
  char* lB0 = (char*)sBh + w * 1024;
  char* lB1 = lB0 + 4096;
  char* lBl0 = (char*)sBl + w * 1024;
  char* lBl1 = lBl0 + 4096;

  const int wr = w >> 1, wc = w & 1;
  const int lr = lane & 15, lg = lane >> 4;
  const int aoff = (wr * 64 + lr) * 32 + lg * 8;
  const int boff = (wc * 64 + lr) * 32 + lg * 8;

  f32x4 acc[4][4];
#pragma unroll
  for (int i = 0; i < 4; i++)
#pragma unroll
    for (int j = 0; j < 4; j++) acc[i][j] = (f32x4)(0.f);

  for (int k0 = 0; k0 < K; k0 += 32) {
    __syncthreads();  // previous iter's ds_reads done before overwrite
    gload16(Ahi + gA0 + k0, lA0);
    gload16(Ahi + gA1 + k0, lA1);
    gload16(Alo + gA0 + k0, lAl0);
    gload16(Alo + gA1 + k0, lAl1);
    gload16(Bhi + gB0 + k0, lB0);
    gload16(Bhi + gB1 + k0, lB1);
    gload16(Blo + gB0 + k0, lBl0);
    gload16(Blo + gB1 + k0, lBl1);
    __syncthreads();  // barrier drains vmcnt -> tiles ready

    f16x8 ah[4], al[4], bh[4], bl[4];
#pragma unroll
    for (int i = 0; i < 4; i++) {
      ah[i] = *(const f16x8*)&sAh[aoff + i * 16 * 32];
      al[i] = *(const f16x8*)&sAl[aoff + i * 16 * 32];
      bh[i] = *(const f16x8*)&sBh[boff + i * 16 * 32];
      bl[i] = *(const f16x8*)&sBl[boff + i * 16 * 32];
    }
#pragma unroll
    for (int i = 0; i < 4; i++)
#pragma unroll
      for (int j = 0; j < 4; j++) {
        acc[i][j] = __builtin_amdgcn_mfma_f32_16x16x32_f16(ah[i], bh[j], acc[i][j], 0, 0, 0);
        acc[i][j] = __builtin_amdgcn_mfma_f32_16x16x32_f16(ah[i], bl[j], acc[i][j], 0, 0, 0);
        acc[i][j] = __builtin_amdgcn_mfma_f32_16x16x32_f16(al[i], bh[j], acc[i][j], 0, 0, 0);
      }
  }

  // C/D layout: col = lane&15, row = (lane>>4)*4 + reg  [m89/m91 verified]
  if constexpr (SPLITOUT) {
    // bias + ELU + f16 hi/lo split (feeds next GEMM's A)
#pragma unroll
    for (int j = 0; j < 4; j++) {
      const int col = n0 + wc * 64 + j * 16 + lr;
      const float bv = bias[col];
#pragma unroll
      for (int i = 0; i < 4; i++) {
        const int rbase = m0 + wr * 64 + i * 16 + lg * 4;
#pragma unroll
        for (int r = 0; r < 4; r++) {
          const int row = rbase + r;
          if (row < M) {
            float o = acc[i][j][r] + bv;
            o = o > 0.f ? o : expm1f(o);
            _Float16 hv = (_Float16)o;
            ohi[(size_t)row * N + col] = hv;
            olo[(size_t)row * N + col] = (_Float16)(o - (float)hv);
          }
        }
      }
    }
  } else {
#pragma unroll
    for (int i = 0; i < 4; i++)
#pragma unroll
      for (int j = 0; j < 4; j++) {
        const int col = n0 + wc * 64 + j * 16 + lr;
        const int rbase = m0 + wr * 64 + i * 16 + lg * 4;
#pragma unroll
        for (int r = 0; r < 4; r++) {
          int row = rbase + r;
          if (row < M) C[(size_t)row * N + col] = acc[i][j][r];
        }
      }

    // fused attention logits (128-col tile lies in one head)
    const int head = n0 / Cdim;
    const int cbase = n0 - head * Cdim + wc * 64 + lr;
    float asv[4], adv[4];
#pragma unroll
    for (int j = 0; j < 4; j++) {
      asv[j] = asrc[(size_t)head * Cdim + cbase + j * 16];
      adv[j] = adst[(size_t)head * Cdim + cbase + j * 16];
    }
#pragma unroll
    for (int i = 0; i < 4; i++) {
      const int rbase = m0 + wr * 64 + i * 16 + lg * 4;
#pragma unroll
      for (int r = 0; r < 4; r++) {
        float ss = 0.f, sd = 0.f;
#pragma unroll
        for (int j = 0; j < 4; j++) {
          float v = acc[i][j][r];
          ss = fmaf(v, asv[j], ss);
          sd = fmaf(v, adv[j], sd);
        }
#pragma unroll
        for (int o = 8; o; o >>= 1) {
          ss += __shfl_xor(ss, o);
          sd += __shfl_xor(sd, o);
        }
        if (lr == 0 && rbase + r < M) {
          atomicAdd(&als[(size_t)(rbase + r) * Hh + head], ss);
          atomicAdd(&ald[(size_t)(rbase + r) * Hh + head], sd);
        }
      }
    }
  }
}

// ---------------- edge softmax passes ----------------
__global__ void edge_max_k(const int* __restrict__ ei,
                           const float* __restrict__ als,
                           const float* __restrict__ ald,
                           float* __restrict__ ev, unsigned* __restrict__ menc,
                           int Hh) {
  int idx = blockIdx.x * blockDim.x + threadIdx.x;
  if (idx >= E_TOT * Hh) return;
  int e = idx / Hh, hh = idx - e * Hh;
  int s, d; edge_sd(ei, e, s, d);
  float x = als[s * Hh + hh] + ald[d * Hh + hh];
  float v = x > 0.f ? x : NEG_SLOPE * x;   // leaky_relu
  ev[idx] = v;
  atomicMax(&menc[d * Hh + hh], enc_f(v));
}

// writes exp values in CSR (dst-sorted) order -> contiguous reads in aggregation
__global__ void edge_exp_k(const int* __restrict__ ei,
                           const unsigned* __restrict__ menc,
                           const float* __restrict__ ev,
                           const int* __restrict__ csr_pos,
                           float* __restrict__ evs, float* __restrict__ denom,
                           int Hh) {
  int idx = blockIdx.x * blockDim.x + threadIdx.x;
  if (idx >= E_TOT * Hh) return;
  int e = idx / Hh, hh = idx - e * Hh;
  int s, d; edge_sd(ei, e, s, d);
  float m = dec_f(menc[d * Hh + hh]);
  float ex = expf(ev[idx] - m);
  evs[(size_t)csr_pos[e] * Hh + hh] = ex;
  atomicAdd(&denom[d * Hh + hh], ex);
}

// ---------------- CSR build (dst-sorted) ----------------
__global__ void hist_k(const int* __restrict__ ei, int* __restrict__ count) {
  int e = blockIdx.x * blockDim.x + threadIdx.x;
  if (e >= E_TOT) return;
  int s, d; edge_sd(ei, e, s, d);
  atomicAdd(&count[d], 1);
}

__global__ __launch_bounds__(1024) void scan_k(const int* __restrict__ count,
                                               int* __restrict__ rowstart,
                                               int N, int total) {
  __shared__ int sums[1024];
  __shared__ int carry_s;
  int t = threadIdx.x;
  if (t == 0) carry_s = 0;
  __syncthreads();
  for (int base = 0; base < N; base += 1024) {
    int i = base + t;
    int c = (i < N) ? count[i] : 0;
    sums[t] = c;
    __syncthreads();
    for (int off = 1; off < 1024; off <<= 1) {
      int v = (t >= off) ? sums[t - off] : 0;
      __syncthreads();
      sums[t] += v;
      __syncthreads();
    }
    int carry = carry_s;
    if (i < N) rowstart[i] = carry + sums[t] - c;  // exclusive
    __syncthreads();
    if (t == 1023) carry_s = carry + sums[1023];
    __syncthreads();
  }
  if (t == 0) rowstart[N] = total;
}

__global__ void scatter_k(const int* __restrict__ ei,
                          const int* __restrict__ rowstart,
                          int* __restrict__ cursor,
                          int* __restrict__ csr_src, int* __restrict__ csr_pos) {
  int e = blockIdx.x * blockDim.x + threadIdx.x;
  if (e >= E_TOT) return;
  int s, d; edge_sd(ei, e, s, d);
  int pos = rowstart[d] + atomicAdd(&cursor[d], 1);
  csr_src[pos] = s;
  csr_pos[e] = pos;   // inverse permutation (edge -> CSR slot)
}

// ---- layer-1 aggregation of RAW x (per head): xa[n,h,:] = sum alpha[e,h] x[s,:]
// writes f16 hi/lo [N][H1][IN_DIM] (GEMM1 A, lda = H1*IN_DIM)
__global__ __launch_bounds__(192) void aggregate_x_k(
    const float* __restrict__ x, const float* __restrict__ evs,
    const float* __restrict__ denom, const int* __restrict__ rowstart,
    const int* __restrict__ csr_src,
    _Float16* __restrict__ ohi, _Float16* __restrict__ olo) {
  const int n = blockIdx.x;
  const int f0 = threadIdx.x * 4;  // < 768
  float inv[H1];
#pragma unroll
  for (int h = 0; h < H1; h++) inv[h] = 1.f / (denom[n * H1 + h] + 1e-16f);
  float acc[H1][4];
#pragma unroll
  for (int h = 0; h < H1; h++)
#pragma unroll
    for (int q = 0; q < 4; q++) acc[h][q] = 0.f;

  const int j0 = rowstart[n], j1 = rowstart[n + 1];
  int j = j0;
  for (; j + 4 <= j1; j += 4) {
    int sidx[4];
    float4 wv[4], xv[4];
#pragma unroll
    for (int u = 0; u < 4; u++) sidx[u] = csr_src[j + u];
#pragma unroll
    for (int u = 0; u < 4; u++) wv[u] = *(const float4*)&evs[(size_t)(j + u) * H1];
#pragma unroll
    for (int u = 0; u < 4; u++)
      xv[u] = *(const float4*)(x + (size_t)sidx[u] * IN_DIM + f0);
#pragma unroll
    for (int u = 0; u < 4; u++) {
      const float* pw = (const float*)&wv[u];
#pragma unroll
      for (int h = 0; h < H1; h++) {
        acc[h][0] = fmaf(pw[h], xv[u].x, acc[h][0]);
        acc[h][1] = fmaf(pw[h], xv[u].y, acc[h][1]);
        acc[h][2] = fmaf(pw[h], xv[u].z, acc[h][2]);
        acc[h][3] = fmaf(pw[h], xv[u].w, acc[h][3]);
      }
    }
  }
  for (; j < j1; j++) {
    int s = csr_src[j];
    float4 wv = *(const float4*)&evs[(size_t)j * H1];
    float4 xv = *(const float4*)(x + (size_t)s * IN_DIM + f0);
    const float* pw = (const float*)&wv;
#pragma unroll
    for (int h = 0; h < H1; h++) {
      acc[h][0] = fmaf(pw[h], xv.x, acc[h][0]);
      acc[h][1] = fmaf(pw[h], xv.y, acc[h][1]);
      acc[h][2] = fmaf(pw[h], xv.z, acc[h][2]);
      acc[h][3] = fmaf(pw[h], xv.w, acc[h][3]);
    }
  }

#pragma unroll
  for (int h = 0; h < H1; h++) {
    f16x4 h4, l4;
#pragma unroll
    for (int q = 0; q < 4; q++) {
      float o = acc[h][q] * inv[h];
      _Float16 hv = (_Float16)o;
      h4[q] = hv;
      l4[q] = (_Float16)(o - (float)hv);
    }
    *(f16x4*)&ohi[(size_t)n * (H1 * IN_DIM) + h * IN_DIM + f0] = h4;
    *(f16x4*)&olo[(size_t)n * (H1 * IN_DIM) + h * IN_DIM + f0] = l4;
  }
}

// ---------------- layer-2 aggregation: out[n,:] = (sum ev*h3[src,:])/denom + b ----
template <int FT>
__global__ __launch_bounds__(256) void aggregate_k(
    const float* __restrict__ hsrc, const float* __restrict__ evs,
    const float* __restrict__ denom, const float* __restrict__ bias,
    const int* __restrict__ rowstart, const int* __restrict__ csr_src,
    float* __restrict__ out, int Hh, int C) {
  const int n = blockIdx.x;
  const int t = threadIdx.x;
  const int F = Hh * C;
  const int f0 = t * FT;
  const int hh = f0 / C;
  const float inv = 1.f / (denom[n * Hh + hh] + 1e-16f);
  float acc[FT];
#pragma unroll
  for (int i = 0; i < FT; i++) acc[i] = 0.f;
  const int j0 = rowstart[n], j1 = rowstart[n + 1];

  constexpr int UN = 8;
  int j = j0;
  for (; j + UN <= j1; j += UN) {
    int   sidx[UN];
    float wv[UN];
#pragma unroll
    for (int u = 0; u < UN; u++) sidx[u] = csr_src[j + u];
#pragma unroll
    for (int u = 0; u < UN; u++) wv[u] = evs[(size_t)(j + u) * Hh + hh];
    float4 va[UN][FT / 4];
#pragma unroll
    for (int u = 0; u < UN; u++) {
      const float* hp = hsrc + (size_t)sidx[u] * F + f0;
#pragma unroll
      for (int q = 0; q < FT / 4; q++) va[u][q] = *(const float4*)(hp + q * 4);
    }
#pragma unroll
    for (int u = 0; u < UN; u++)
#pragma unroll
      for (int q = 0; q < FT / 4; q++) {
        acc[q * 4 + 0] = fmaf(wv[u], va[u][q].x, acc[q * 4 + 0]);
        acc[q * 4 + 1] = fmaf(wv[u], va[u][q].y, acc[q * 4 + 1]);
        acc[q * 4 + 2] = fmaf(wv[u], va[u][q].z, acc[q * 4 + 2]);
        acc[q * 4 + 3] = fmaf(wv[u], va[u][q].w, acc[q * 4 + 3]);
      }
  }
  for (; j < j1; j++) {
    int s = csr_src[j];
    float wgt = evs[(size_t)j * Hh + hh];
    const float* hp = hsrc + (size_t)s * F + f0;
#pragma unroll
    for (int q = 0; q < FT / 4; q++) {
      float4 v = *(const float4*)(hp + q * 4);
      acc[q * 4 + 0] = fmaf(wgt, v.x, acc[q * 4 + 0]);
      acc[q * 4 + 1] = fmaf(wgt, v.y, acc[q * 4 + 1]);
      acc[q * 4 + 2] = fmaf(wgt, v.z, acc[q * 4 + 2]);
      acc[q * 4 + 3] = fmaf(wgt, v.w, acc[q * 4 + 3]);
    }
  }
#pragma unroll
  for (int i = 0; i < FT; i++)
    out[(size_t)n * F + f0 + i] = acc[i] * inv + bias[f0 + i];
}

// ---------------- launch ----------------
extern "C" void kernel_launch(void* const* d_in, const int* in_sizes, int n_in,
                              void* d_out, int out_size, void* d_ws, size_t ws_size,
                              hipStream_t stream) {
  const float* x   = (const float*)d_in[0];
  const int*   ei  = (const int*)d_in[1];   // [2, 160000]; JAX x64 off -> int32
  const float* W1  = (const float*)d_in[2];
  const float* as1 = (const float*)d_in[3];
  const float* ad1 = (const float*)d_in[4];
  const float* b1  = (const float*)d_in[5];
  const float* W2  = (const float*)d_in[6];
  const float* as2 = (const float*)d_in[7];
  const float* ad2 = (const float*)d_in[8];
  const float* b2  = (const float*)d_in[9];
  float* out = (float*)d_out;

  char* p = (char*)d_ws;
  auto alloc = [&](size_t bytes) {
    char* r = p;
    p += (bytes + 255) & ~(size_t)255;
    return r;
  };
  _Float16* xahi  = (_Float16*)alloc((size_t)N_NODES * H1 * IN_DIM * 2);  // 61.4 MB
  _Float16* xalo  = (_Float16*)alloc((size_t)N_NODES * H1 * IN_DIM * 2);
  _Float16* W1hi  = (_Float16*)alloc((size_t)IN_DIM * F1 * 2);            // [F1][IN_DIM]
  _Float16* W1lo  = (_Float16*)alloc((size_t)IN_DIM * F1 * 2);
  _Float16* W2hi  = (_Float16*)alloc((size_t)F1 * C2 * 2);                // [C2][F1]
  _Float16* W2lo  = (_Float16*)alloc((size_t)F1 * C2 * 2);
  _Float16* h2hi  = (_Float16*)alloc((size_t)N_NODES * F1 * 2);           // 41 MB
  _Float16* h2lo  = (_Float16*)alloc((size_t)N_NODES * F1 * 2);
  float*    ws1   = (float*)alloc((size_t)H1 * IN_DIM * 4);
  float*    wd1   = (float*)alloc((size_t)H1 * IN_DIM * 4);
  float*    als   = (float*)alloc((size_t)N_NODES * H1 * 4);
  float*    ald   = (float*)alloc((size_t)N_NODES * H1 * 4);
  unsigned* menc  = (unsigned*)alloc((size_t)N_NODES * H1 * 4);
  float*    denom = (float*)alloc((size_t)N_NODES * H1 * 4);
  float*    ev    = (float*)alloc((size_t)E_TOT * H1 * 4);
  float*    evs   = (float*)alloc((size_t)E_TOT * H1 * 4);
  int*      count    = (int*)alloc((size_t)N_NODES * 4);
  int*      rowstart = (int*)alloc((size_t)(N_NODES + 1) * 4);
  int*      cursor   = (int*)alloc((size_t)N_NODES * 4);
  int*      csr_src  = (int*)alloc((size_t)E_TOT * 4);
  int*      csr_pos  = (int*)alloc((size_t)E_TOT * 4);
  float*    h3 = (float*)xahi;  // xa dead after GEMM1; alias (30.7 <= 61.4 MB)

  const int EB = (E_TOT + 255) / 256;

  // CSR by destination (same graph both layers)
  hipMemsetAsync(count, 0, (size_t)N_NODES * 4, stream);
  hipMemsetAsync(cursor, 0, (size_t)N_NODES * 4, stream);
  hist_k<<<EB, 256, 0, stream>>>(ei, count);
  scan_k<<<1, 1024, 0, stream>>>(count, rowstart, N_NODES, E_TOT);
  scatter_k<<<EB, 256, 0, stream>>>(ei, rowstart, cursor, csr_src, csr_pos);

  // weight conversions + projected attn vectors
  tsplit_k<<<dim3(F1 / 32, IN_DIM / 32), dim3(32, 8), 0, stream>>>(W1, W1hi, W1lo,
                                                                   IN_DIM, F1);
  tsplit_k<<<dim3(C2 / 32, F1 / 32), dim3(32, 8), 0, stream>>>(W2, W2hi, W2lo,
                                                               F1, C2);
  proj_attn_k<<<(H1 * IN_DIM * 64) / 256, 256, 0, stream>>>(W1, as1, ad1, ws1, wd1);

  // ---- layer 1 (aggregate-then-project) ----
  logits1_k<<<(N_NODES * 64 + 255) / 256, 256, 0, stream>>>(x, ws1, wd1, als, ald);
  hipMemsetAsync(menc, 0, (size_t)N_NODES * H1 * 4, stream);
  hipMemsetAsync(denom, 0, (size_t)N_NODES * H1 * 4, stream);
  edge_max_k<<<(E_TOT * H1 + 255) / 256, 256, 0, stream>>>(ei, als, ald, ev, menc, H1);
  edge_exp_k<<<(E_TOT * H1 + 255) / 256, 256, 0, stream>>>(ei, menc, ev, csr_pos,
                                                           evs, denom, H1);
  aggregate_x_k<<<N_NODES, 192, 0, stream>>>(x, evs, denom, rowstart, csr_src,
                                             xahi, xalo);
  // h2 = ELU(xa @ W1 + b1), written as f16 hi/lo
  gemm_sf16<true><<<dim3(F1 / 128, (N_NODES + 127) / 128), 256, 0, stream>>>(
      xahi, xalo, W1hi, W1lo, N_NODES, F1, IN_DIM, H1 * IN_DIM, C1,
      nullptr, b1, h2hi, h2lo, nullptr, nullptr, nullptr, nullptr, 0, C1);

  // ---- layer 2 (project-then-aggregate, fused logits) ----
  hipMemsetAsync(als, 0, (size_t)N_NODES * 4, stream);
  hipMemsetAsync(ald, 0, (size_t)N_NODES * 4, stream);
  gemm_sf16<false><<<dim3(C2 / 128, (N_NODES + 127) / 128), 256, 0, stream>>>(
      h2hi, h2lo, W2hi, W2lo, N_NODES, C2, F1, F1, 1 << 30,
      h3, nullptr, nullptr, nullptr, as2, ad2, als, ald, 1, C2);
  hipMemsetAsync(menc, 0, (size_t)N_NODES * 4, stream);
  hipMemsetAsync(denom, 0, (size_t)N_NODES * 4, stream);
  edge_max_k<<<EB, 256, 0, stream>>>(ei, als, ald, ev, menc, 1);
  edge_exp_k<<<EB, 256, 0, stream>>>(ei, menc, ev, csr_pos, evs, denom, 1);
  aggregate_k<4><<<N_NODES, 192, 0, stream>>>(h3, evs, denom, b2, rowstart,
                                              csr_src, out, 1, C2);
}

// Round 5
// 637.637 us; speedup vs baseline: 1.1568x; 1.0046x over previous
//
#include <hip/hip_runtime.h>
#include <hip/hip_bf16.h>
#include <math.h>

// ---------------- problem constants ----------------
#define N_NODES 10000
#define N_EDGES0 160000
#define E_TOT (N_EDGES0 + N_NODES)   // + self loops
#define H1 4
#define C1 512
#define F1 2048                      // H1*C1
#define IN_DIM 768
#define C2 768
#define NEG_SLOPE 0.2f

typedef _Float16 f16x8 __attribute__((ext_vector_type(8)));
typedef _Float16 f16x4 __attribute__((ext_vector_type(4)));
typedef float f32x4 __attribute__((ext_vector_type(4)));

typedef __attribute__((address_space(1))) const void* gas_ptr;
typedef __attribute__((address_space(3))) void* las_ptr;
static __device__ __forceinline__ void gload16(const void* g, void* l) {
  __builtin_amdgcn_global_load_lds((gas_ptr)g, (las_ptr)l, 16, 0, 0);
}

// Monotonic float<->unsigned encoding so atomicMax works for signed floats.
static __device__ __forceinline__ unsigned enc_f(float v) {
  unsigned u = __float_as_uint(v);
  return (u & 0x80000000u) ? ~u : (u | 0x80000000u);
}
static __device__ __forceinline__ float dec_f(unsigned u) {
  return (u & 0x80000000u) ? __uint_as_float(u ^ 0x80000000u)
                           : __uint_as_float(~u);
}

// edge e -> (src, dst); e >= N_EDGES0 are the implicit self-loops
static __device__ __forceinline__ void edge_sd(const int* __restrict__ ei, int e,
                                               int& s, int& d) {
  if (e < N_EDGES0) { s = ei[e]; d = ei[N_EDGES0 + e]; }
  else { s = e - N_EDGES0; d = s; }
}

// ---------------- W [K][N] fp32 -> W^T [N][K] f16 hi/lo ---------------------
__global__ void tsplit_k(const float* __restrict__ W, _Float16* __restrict__ hi,
                         _Float16* __restrict__ lo, int K, int N) {
  __shared__ float tile[32][33];
  const int nb = blockIdx.x * 32, kb = blockIdx.y * 32;
  const int tx = threadIdx.x, ty = threadIdx.y;  // 32 x 8
  for (int r = ty; r < 32; r += 8)
    tile[r][tx] = W[(size_t)(kb + r) * N + nb + tx];
  __syncthreads();
  for (int r = ty; r < 32; r += 8) {
    float v = tile[tx][r];  // = W[kb+tx][nb+r]
    _Float16 h = (_Float16)v;
    hi[(size_t)(nb + r) * K + kb + tx] = h;
    lo[(size_t)(nb + r) * K + kb + tx] = (_Float16)(v - (float)h);
  }
}

// ---- layer-1 attn vectors projected into x-space: ws[h,k] = sum_c W1[k,h*C1+c]*a[h,c]
__global__ void proj_attn_k(const float* __restrict__ W1,
                            const float* __restrict__ as1,
                            const float* __restrict__ ad1,
                            float* __restrict__ ws, float* __restrict__ wd) {
  int wv = (blockIdx.x * blockDim.x + threadIdx.x) >> 6;
  int lane = threadIdx.x & 63;
  if (wv >= H1 * IN_DIM) return;
  int h = wv / IN_DIM, k = wv - h * IN_DIM;
  const float* wrow = W1 + (size_t)k * F1 + h * C1;
  const float* sa = as1 + h * C1;
  const float* da = ad1 + h * C1;
  float ss = 0.f, sd = 0.f;
  for (int c = lane; c < C1; c += 64) {
    float v = wrow[c];
    ss = fmaf(v, sa[c], ss);
    sd = fmaf(v, da[c], sd);
  }
#pragma unroll
  for (int o = 32; o; o >>= 1) { ss += __shfl_xor(ss, o); sd += __shfl_xor(sd, o); }
  if (lane == 0) { ws[(size_t)h * IN_DIM + k] = ss; wd[(size_t)h * IN_DIM + k] = sd; }
}

// ---- layer-1 logits from raw x: als[n,h] = x[n,:] . ws[h,:]
__global__ void logits1_k(const float* __restrict__ x,
                          const float* __restrict__ ws, const float* __restrict__ wd,
                          float* __restrict__ als, float* __restrict__ ald) {
  int n = (blockIdx.x * blockDim.x + threadIdx.x) >> 6;
  int lane = threadIdx.x & 63;
  if (n >= N_NODES) return;
  const float* xp = x + (size_t)n * IN_DIM;
  float ss[H1] = {0.f, 0.f, 0.f, 0.f}, sd[H1] = {0.f, 0.f, 0.f, 0.f};
  for (int k = lane; k < IN_DIM; k += 64) {
    float xv = xp[k];
#pragma unroll
    for (int h = 0; h < H1; h++) {
      ss[h] = fmaf(xv, ws[h * IN_DIM + k], ss[h]);
      sd[h] = fmaf(xv, wd[h * IN_DIM + k], sd[h]);
    }
  }
#pragma unroll
  for (int h = 0; h < H1; h++)
#pragma unroll
    for (int o = 32; o; o >>= 1) { ss[h] += __shfl_xor(ss[h], o); sd[h] += __shfl_xor(sd[h], o); }
  if (lane == 0) {
#pragma unroll
    for (int h = 0; h < H1; h++) {
      als[(size_t)n * H1 + h] = ss[h];
      ald[(size_t)n * H1 + h] = sd[h];
    }
  }
}

// ---------------- split-f16 MFMA GEMM: C[M,N] = A[M,K] @ Bt[N,K]^T ----------
// LDS bank-conflict fix (T2 adapted to global_load_lds): LDS granule
// (row, g') holds global granule (row, g) with g' = (g + (row>>1)) & 3.
// Stage: linear LDS dest + inverse-swizzled GLOBAL source (m173/m201 pattern).
// Read: lgs = (lg + (lr>>1)) & 3  (lane-constant; wr*64, i*16 vanish mod 4
// after >>1). Turns the 8-way quarter-wave conflict into free 2-way.
template <bool SPLITOUT>
__global__ __launch_bounds__(256) void gemm_sf16(
    const _Float16* __restrict__ Ahi, const _Float16* __restrict__ Alo,
    const _Float16* __restrict__ Bhi, const _Float16* __restrict__ Blo,
    int M, int N, int K, int lda, int nch,
    float* __restrict__ C, const float* __restrict__ bias,
    _Float16* __restrict__ ohi, _Float16* __restrict__ olo,
    const float* __restrict__ asrc, const float* __restrict__ adst,
    float* __restrict__ als, float* __restrict__ ald, int Hh, int Cdim) {
  __shared__ _Float16 sAh[128 * 32];
  __shared__ _Float16 sAl[128 * 32];
  __shared__ _Float16 sBh[128 * 32];
  __shared__ _Float16 sBl[128 * 32];

  const int t = threadIdx.x;
  const int w = t >> 6, lane = t & 63;
  const int m0 = blockIdx.y * 128, n0 = blockIdx.x * 128;
  const size_t hofs = (size_t)(n0 / nch) * K;

  // staging decomposition: chunk i covers LDS bytes [w*1024 + i*4096, +1024)
  const int o0 = w * 1024 + lane * 16;
  const int o1 = o0 + 4096;
  const int ma0 = o0 >> 6;                 // row (64B rows); cb identical o0/o1
  const int ma1 = o1 >> 6;
  // inverse-swizzled source granule: g = (g' - (row>>1)) & 3,
  // g' = lane&3, (row>>1)&3 = (lane>>3)&3  (same for both chunks)
  const int gsrc = ((lane & 3) - ((lane >> 3) & 3)) & 3;
  const int rA0 = min(m0 + ma0, M - 1), rA1 = min(m0 + ma1, M - 1);
  const size_t gA0 = (size_t)rA0 * lda + hofs + gsrc * 8;
  const size_t gA1 = (size_t)rA1 * lda + hofs + gsrc * 8;
  const size_t gB0 = (size_t)(n0 + ma0) * K + gsrc * 8;
  const size_t gB1 = (size_t)(n0 + ma1) * K + gsrc * 8;

  char* lA0 = (char*)sAh + w * 1024;           // wave-uniform LDS bases
  char* lA1 = lA0 + 4096;
  char* lAl0 = (char*)sAl + w * 1024;
  char* lAl1 = lAl0 + 4096;
  char* lB0 = (char*)sBh + w * 1024;
  char* lB1 = lB0 + 4096;
  char* lBl0 = (char*)sBl + w * 1024;
  char* lBl1 = lBl0 + 4096;

  const int wr = w >> 1, wc = w & 1;
  const int lr = lane & 15, lg = lane >> 4;
  const int lgs = (lg + (lr >> 1)) & 3;        // swizzled read granule
  const int aoff = (wr * 64 + lr) * 32 + lgs * 8;
  const int boff = (wc * 64 + lr) * 32 + lgs * 8;

  f32x4 acc[4][4];
#pragma unroll
  for (int i = 0; i < 4; i++)
#pragma unroll
    for (int j = 0; j < 4; j++) acc[i][j] = (f32x4)(0.f);

  for (int k0 = 0; k0 < K; k0 += 32) {
    __syncthreads();  // previous iter's ds_reads done before overwrite
    gload16(Ahi + gA0 + k0, lA0);
    gload16(Ahi + gA1 + k0, lA1);
    gload16(Alo + gA0 + k0, lAl0);
    gload16(Alo + gA1 + k0, lAl1);
    gload16(Bhi + gB0 + k0, lB0);
    gload16(Bhi + gB1 + k0, lB1);
    gload16(Blo + gB0 + k0, lBl0);
    gload16(Blo + gB1 + k0, lBl1);
    __syncthreads();  // barrier drains vmcnt -> tiles ready

    f16x8 ah[4], al[4], bh[4], bl[4];
#pragma unroll
    for (int i = 0; i < 4; i++) {
      ah[i] = *(const f16x8*)&sAh[aoff + i * 16 * 32];
      al[i] = *(const f16x8*)&sAl[aoff + i * 16 * 32];
      bh[i] = *(const f16x8*)&sBh[boff + i * 16 * 32];
      bl[i] = *(const f16x8*)&sBl[boff + i * 16 * 32];
    }
#pragma unroll
    for (int i = 0; i < 4; i++)
#pragma unroll
      for (int j = 0; j < 4; j++) {
        acc[i][j] = __builtin_amdgcn_mfma_f32_16x16x32_f16(ah[i], bh[j], acc[i][j], 0, 0, 0);
        acc[i][j] = __builtin_amdgcn_mfma_f32_16x16x32_f16(ah[i], bl[j], acc[i][j], 0, 0, 0);
        acc[i][j] = __builtin_amdgcn_mfma_f32_16x16x32_f16(al[i], bh[j], acc[i][j], 0, 0, 0);
      }
  }

  // C/D layout: col = lane&15, row = (lane>>4)*4 + reg  [m89/m91 verified]
  if constexpr (SPLITOUT) {
    // bias + ELU + f16 hi/lo split (feeds next GEMM's A)
#pragma unroll
    for (int j = 0; j < 4; j++) {
      const int col = n0 + wc * 64 + j * 16 + lr;
      const float bv = bias[col];
#pragma unroll
      for (int i = 0; i < 4; i++) {
        const int rbase = m0 + wr * 64 + i * 16 + lg * 4;
#pragma unroll
        for (int r = 0; r < 4; r++) {
          const int row = rbase + r;
          if (row < M) {
            float o = acc[i][j][r] + bv;
            o = o > 0.f ? o : expm1f(o);
            _Float16 hv = (_Float16)o;
            ohi[(size_t)row * N + col] = hv;
            olo[(size_t)row * N + col] = (_Float16)(o - (float)hv);
          }
        }
      }
    }
  } else {
#pragma unroll
    for (int i = 0; i < 4; i++)
#pragma unroll
      for (int j = 0; j < 4; j++) {
        const int col = n0 + wc * 64 + j * 16 + lr;
        const int rbase = m0 + wr * 64 + i * 16 + lg * 4;
#pragma unroll
        for (int r = 0; r < 4; r++) {
          int row = rbase + r;
          if (row < M) C[(size_t)row * N + col] = acc[i][j][r];
        }
      }

    // fused attention logits (128-col tile lies in one head)
    const int head = n0 / Cdim;
    const int cbase = n0 - head * Cdim + wc * 64 + lr;
    float asv[4], adv[4];
#pragma unroll
    for (int j = 0; j < 4; j++) {
      asv[j] = asrc[(size_t)head * Cdim + cbase + j * 16];
      adv[j] = adst[(size_t)head * Cdim + cbase + j * 16];
    }
#pragma unroll
    for (int i = 0; i < 4; i++) {
      const int rbase = m0 + wr * 64 + i * 16 + lg * 4;
#pragma unroll
      for (int r = 0; r < 4; r++) {
        float ss = 0.f, sd = 0.f;
#pragma unroll
        for (int j = 0; j < 4; j++) {
          float v = acc[i][j][r];
          ss = fmaf(v, asv[j], ss);
          sd = fmaf(v, adv[j], sd);
        }
#pragma unroll
        for (int o = 8; o; o >>= 1) {
          ss += __shfl_xor(ss, o);
          sd += __shfl_xor(sd, o);
        }
        if (lr == 0 && rbase + r < M) {
          atomicAdd(&als[(size_t)(rbase + r) * Hh + head], ss);
          atomicAdd(&ald[(size_t)(rbase + r) * Hh + head], sd);
        }
      }
    }
  }
}

// ---------------- edge softmax passes ----------------
__global__ void edge_max_k(const int* __restrict__ ei,
                           const float* __restrict__ als,
                           const float* __restrict__ ald,
                           float* __restrict__ ev, unsigned* __restrict__ menc,
                           int Hh) {
  int idx = blockIdx.x * blockDim.x + threadIdx.x;
  if (idx >= E_TOT * Hh) return;
  int e = idx / Hh, hh = idx - e * Hh;
  int s, d; edge_sd(ei, e, s, d);
  float x = als[s * Hh + hh] + ald[d * Hh + hh];
  float v = x > 0.f ? x : NEG_SLOPE * x;   // leaky_relu
  ev[idx] = v;
  atomicMax(&menc[d * Hh + hh], enc_f(v));
}

// writes exp values in CSR (dst-sorted) order -> contiguous reads in aggregation
__global__ void edge_exp_k(const int* __restrict__ ei,
                           const unsigned* __restrict__ menc,
                           const float* __restrict__ ev,
                           const int* __restrict__ csr_pos,
                           float* __restrict__ evs, float* __restrict__ denom,
                           int Hh) {
  int idx = blockIdx.x * blockDim.x + threadIdx.x;
  if (idx >= E_TOT * Hh) return;
  int e = idx / Hh, hh = idx - e * Hh;
  int s, d; edge_sd(ei, e, s, d);
  float m = dec_f(menc[d * Hh + hh]);
  float ex = expf(ev[idx] - m);
  evs[(size_t)csr_pos[e] * Hh + hh] = ex;
  atomicAdd(&denom[d * Hh + hh], ex);
}

// ---------------- CSR build (dst-sorted) ----------------
__global__ void hist_k(const int* __restrict__ ei, int* __restrict__ count) {
  int e = blockIdx.x * blockDim.x + threadIdx.x;
  if (e >= E_TOT) return;
  int s, d; edge_sd(ei, e, s, d);
  atomicAdd(&count[d], 1);
}

__global__ __launch_bounds__(1024) void scan_k(const int* __restrict__ count,
                                               int* __restrict__ rowstart,
                                               int N, int total) {
  __shared__ int sums[1024];
  __shared__ int carry_s;
  int t = threadIdx.x;
  if (t == 0) carry_s = 0;
  __syncthreads();
  for (int base = 0; base < N; base += 1024) {
    int i = base + t;
    int c = (i < N) ? count[i] : 0;
    sums[t] = c;
    __syncthreads();
    for (int off = 1; off < 1024; off <<= 1) {
      int v = (t >= off) ? sums[t - off] : 0;
      __syncthreads();
      sums[t] += v;
      __syncthreads();
    }
    int carry = carry_s;
    if (i < N) rowstart[i] = carry + sums[t] - c;  // exclusive
    __syncthreads();
    if (t == 1023) carry_s = carry + sums[1023];
    __syncthreads();
  }
  if (t == 0) rowstart[N] = total;
}

__global__ void scatter_k(const int* __restrict__ ei,
                          const int* __restrict__ rowstart,
                          int* __restrict__ cursor,
                          int* __restrict__ csr_src, int* __restrict__ csr_pos) {
  int e = blockIdx.x * blockDim.x + threadIdx.x;
  if (e >= E_TOT) return;
  int s, d; edge_sd(ei, e, s, d);
  int pos = rowstart[d] + atomicAdd(&cursor[d], 1);
  csr_src[pos] = s;
  csr_pos[e] = pos;   // inverse permutation (edge -> CSR slot)
}

// ---- layer-1 aggregation of RAW x (per head): xa[n,h,:] = sum alpha[e,h] x[s,:]
// writes f16 hi/lo [N][H1][IN_DIM] (GEMM1 A, lda = H1*IN_DIM)
__global__ __launch_bounds__(192) void aggregate_x_k(
    const float* __restrict__ x, const float* __restrict__ evs,
    const float* __restrict__ denom, const int* __restrict__ rowstart,
    const int* __restrict__ csr_src,
    _Float16* __restrict__ ohi, _Float16* __restrict__ olo) {
  const int n = blockIdx.x;
  const int f0 = threadIdx.x * 4;  // < 768
  float inv[H1];
#pragma unroll
  for (int h = 0; h < H1; h++) inv[h] = 1.f / (denom[n * H1 + h] + 1e-16f);
  float acc[H1][4];
#pragma unroll
  for (int h = 0; h < H1; h++)
#pragma unroll
    for (int q = 0; q < 4; q++) acc[h][q] = 0.f;

  const int j0 = rowstart[n], j1 = rowstart[n + 1];
  int j = j0;
  for (; j + 4 <= j1; j += 4) {
    int sidx[4];
    float4 wv[4], xv[4];
#pragma unroll
    for (int u = 0; u < 4; u++) sidx[u] = csr_src[j + u];
#pragma unroll
    for (int u = 0; u < 4; u++) wv[u] = *(const float4*)&evs[(size_t)(j + u) * H1];
#pragma unroll
    for (int u = 0; u < 4; u++)
      xv[u] = *(const float4*)(x + (size_t)sidx[u] * IN_DIM + f0);
#pragma unroll
    for (int u = 0; u < 4; u++) {
      const float* pw = (const float*)&wv[u];
#pragma unroll
      for (int h = 0; h < H1; h++) {
        acc[h][0] = fmaf(pw[h], xv[u].x, acc[h][0]);
        acc[h][1] = fmaf(pw[h], xv[u].y, acc[h][1]);
        acc[h][2] = fmaf(pw[h], xv[u].z, acc[h][2]);
        acc[h][3] = fmaf(pw[h], xv[u].w, acc[h][3]);
      }
    }
  }
  for (; j < j1; j++) {
    int s = csr_src[j];
    float4 wv = *(const float4*)&evs[(size_t)j * H1];
    float4 xv = *(const float4*)(x + (size_t)s * IN_DIM + f0);
    const float* pw = (const float*)&wv;
#pragma unroll
    for (int h = 0; h < H1; h++) {
      acc[h][0] = fmaf(pw[h], xv.x, acc[h][0]);
      acc[h][1] = fmaf(pw[h], xv.y, acc[h][1]);
      acc[h][2] = fmaf(pw[h], xv.z, acc[h][2]);
      acc[h][3] = fmaf(pw[h], xv.w, acc[h][3]);
    }
  }

#pragma unroll
  for (int h = 0; h < H1; h++) {
    f16x4 h4, l4;
#pragma unroll
    for (int q = 0; q < 4; q++) {
      float o = acc[h][q] * inv[h];
      _Float16 hv = (_Float16)o;
      h4[q] = hv;
      l4[q] = (_Float16)(o - (float)hv);
    }
    *(f16x4*)&ohi[(size_t)n * (H1 * IN_DIM) + h * IN_DIM + f0] = h4;
    *(f16x4*)&olo[(size_t)n * (H1 * IN_DIM) + h * IN_DIM + f0] = l4;
  }
}

// ---------------- layer-2 aggregation: out[n,:] = (sum ev*h3[src,:])/denom + b ----
template <int FT>
__global__ __launch_bounds__(256) void aggregate_k(
    const float* __restrict__ hsrc, const float* __restrict__ evs,
    const float* __restrict__ denom, const float* __restrict__ bias,
    const int* __restrict__ rowstart, const int* __restrict__ csr_src,
    float* __restrict__ out, int Hh, int C) {
  const int n = blockIdx.x;
  const int t = threadIdx.x;
  const int F = Hh * C;
  const int f0 = t * FT;
  const int hh = f0 / C;
  const float inv = 1.f / (denom[n * Hh + hh] + 1e-16f);
  float acc[FT];
#pragma unroll
  for (int i = 0; i < FT; i++) acc[i] = 0.f;
  const int j0 = rowstart[n], j1 = rowstart[n + 1];

  constexpr int UN = 8;
  int j = j0;
  for (; j + UN <= j1; j += UN) {
    int   sidx[UN];
    float wv[UN];
#pragma unroll
    for (int u = 0; u < UN; u++) sidx[u] = csr_src[j + u];
#pragma unroll
    for (int u = 0; u < UN; u++) wv[u] = evs[(size_t)(j + u) * Hh + hh];
    float4 va[UN][FT / 4];
#pragma unroll
    for (int u = 0; u < UN; u++) {
      const float* hp = hsrc + (size_t)sidx[u] * F + f0;
#pragma unroll
      for (int q = 0; q < FT / 4; q++) va[u][q] = *(const float4*)(hp + q * 4);
    }
#pragma unroll
    for (int u = 0; u < UN; u++)
#pragma unroll
      for (int q = 0; q < FT / 4; q++) {
        acc[q * 4 + 0] = fmaf(wv[u], va[u][q].x, acc[q * 4 + 0]);
        acc[q * 4 + 1] = fmaf(wv[u], va[u][q].y, acc[q * 4 + 1]);
        acc[q * 4 + 2] = fmaf(wv[u], va[u][q].z, acc[q * 4 + 2]);
        acc[q * 4 + 3] = fmaf(wv[u], va[u][q].w, acc[q * 4 + 3]);
      }
  }
  for (; j < j1; j++) {
    int s = csr_src[j];
    float wgt = evs[(size_t)j * Hh + hh];
    const float* hp = hsrc + (size_t)s * F + f0;
#pragma unroll
    for (int q = 0; q < FT / 4; q++) {
      float4 v = *(const float4*)(hp + q * 4);
      acc[q * 4 + 0] = fmaf(wgt, v.x, acc[q * 4 + 0]);
      acc[q * 4 + 1] = fmaf(wgt, v.y, acc[q * 4 + 1]);
      acc[q * 4 + 2] = fmaf(wgt, v.z, acc[q * 4 + 2]);
      acc[q * 4 + 3] = fmaf(wgt, v.w, acc[q * 4 + 3]);
    }
  }
#pragma unroll
  for (int i = 0; i < FT; i++)
    out[(size_t)n * F + f0 + i] = acc[i] * inv + bias[f0 + i];
}

// ---------------- launch ----------------
extern "C" void kernel_launch(void* const* d_in, const int* in_sizes, int n_in,
                              void* d_out, int out_size, void* d_ws, size_t ws_size,
                              hipStream_t stream) {
  const float* x   = (const float*)d_in[0];
  const int*   ei  = (const int*)d_in[1];   // [2, 160000]; JAX x64 off -> int32
  const float* W1  = (const float*)d_in[2];
  const float* as1 = (const float*)d_in[3];
  const float* ad1 = (const float*)d_in[4];
  const float* b1  = (const float*)d_in[5];
  const float* W2  = (const float*)d_in[6];
  const float* as2 = (const float*)d_in[7];
  const float* ad2 = (const float*)d_in[8];
  const float* b2  = (const float*)d_in[9];
  float* out = (float*)d_out;

  char* p = (char*)d_ws;
  auto alloc = [&](size_t bytes) {
    char* r = p;
    p += (bytes + 255) & ~(size_t)255;
    return r;
  };
  _Float16* xahi  = (_Float16*)alloc((size_t)N_NODES * H1 * IN_DIM * 2);  // 61.4 MB
  _Float16* xalo  = (_Float16*)alloc((size_t)N_NODES * H1 * IN_DIM * 2);
  _Float16* W1hi  = (_Float16*)alloc((size_t)IN_DIM * F1 * 2);            // [F1][IN_DIM]
  _Float16* W1lo  = (_Float16*)alloc((size_t)IN_DIM * F1 * 2);
  _Float16* W2hi  = (_Float16*)alloc((size_t)F1 * C2 * 2);                // [C2][F1]
  _Float16* W2lo  = (_Float16*)alloc((size_t)F1 * C2 * 2);
  _Float16* h2hi  = (_Float16*)alloc((size_t)N_NODES * F1 * 2);           // 41 MB
  _Float16* h2lo  = (_Float16*)alloc((size_t)N_NODES * F1 * 2);
  float*    ws1   = (float*)alloc((size_t)H1 * IN_DIM * 4);
  float*    wd1   = (float*)alloc((size_t)H1 * IN_DIM * 4);
  float*    als   = (float*)alloc((size_t)N_NODES * H1 * 4);
  float*    ald   = (float*)alloc((size_t)N_NODES * H1 * 4);
  unsigned* menc  = (unsigned*)alloc((size_t)N_NODES * H1 * 4);
  float*    denom = (float*)alloc((size_t)N_NODES * H1 * 4);
  float*    ev    = (float*)alloc((size_t)E_TOT * H1 * 4);
  float*    evs   = (float*)alloc((size_t)E_TOT * H1 * 4);
  int*      count    = (int*)alloc((size_t)N_NODES * 4);
  int*      rowstart = (int*)alloc((size_t)(N_NODES + 1) * 4);
  int*      cursor   = (int*)alloc((size_t)N_NODES * 4);
  int*      csr_src  = (int*)alloc((size_t)E_TOT * 4);
  int*      csr_pos  = (int*)alloc((size_t)E_TOT * 4);
  float*    h3 = (float*)xahi;  // xa dead after GEMM1; alias (30.7 <= 61.4 MB)

  const int EB = (E_TOT + 255) / 256;

  // CSR by destination (same graph both layers)
  hipMemsetAsync(count, 0, (size_t)N_NODES * 4, stream);
  hipMemsetAsync(cursor, 0, (size_t)N_NODES * 4, stream);
  hist_k<<<EB, 256, 0, stream>>>(ei, count);
  scan_k<<<1, 1024, 0, stream>>>(count, rowstart, N_NODES, E_TOT);
  scatter_k<<<EB, 256, 0, stream>>>(ei, rowstart, cursor, csr_src, csr_pos);

  // weight conversions + projected attn vectors
  tsplit_k<<<dim3(F1 / 32, IN_DIM / 32), dim3(32, 8), 0, stream>>>(W1, W1hi, W1lo,
                                                                   IN_DIM, F1);
  tsplit_k<<<dim3(C2 / 32, F1 / 32), dim3(32, 8), 0, stream>>>(W2, W2hi, W2lo,
                                                               F1, C2);
  proj_attn_k<<<(H1 * IN_DIM * 64) / 256, 256, 0, stream>>>(W1, as1, ad1, ws1, wd1);

  // ---- layer 1 (aggregate-then-project) ----
  logits1_k<<<(N_NODES * 64 + 255) / 256, 256, 0, stream>>>(x, ws1, wd1, als, ald);
  hipMemsetAsync(menc, 0, (size_t)N_NODES * H1 * 4, stream);
  hipMemsetAsync(denom, 0, (size_t)N_NODES * H1 * 4, stream);
  edge_max_k<<<(E_TOT * H1 + 255) / 256, 256, 0, stream>>>(ei, als, ald, ev, menc, H1);
  edge_exp_k<<<(E_TOT * H1 + 255) / 256, 256, 0, stream>>>(ei, menc, ev, csr_pos,
                                                           evs, denom, H1);
  aggregate_x_k<<<N_NODES, 192, 0, stream>>>(x, evs, denom, rowstart, csr_src,
                                             xahi, xalo);
  // h2 = ELU(xa @ W1 + b1), written as f16 hi/lo
  gemm_sf16<true><<<dim3(F1 / 128, (N_NODES + 127) / 128), 256, 0, stream>>>(
      xahi, xalo, W1hi, W1lo, N_NODES, F1, IN_DIM, H1 * IN_DIM, C1,
      nullptr, b1, h2hi, h2lo, nullptr, nullptr, nullptr, nullptr, 0, C1);

  // ---- layer 2 (project-then-aggregate, fused logits) ----
  hipMemsetAsync(als, 0, (size_t)N_NODES * 4, stream);
  hipMemsetAsync(ald, 0, (size_t)N_NODES * 4, stream);
  gemm_sf16<false><<<dim3(C2 / 128, (N_NODES + 127) / 128), 256, 0, stream>>>(
      h2hi, h2lo, W2hi, W2lo, N_NODES, C2, F1, F1, 1 << 30,
      h3, nullptr, nullptr, nullptr, as2, ad2, als, ald, 1, C2);
  hipMemsetAsync(menc, 0, (size_t)N_NODES * 4, stream);
  hipMemsetAsync(denom, 0, (size_t)N_NODES * 4, stream);
  edge_max_k<<<EB, 256, 0, stream>>>(ei, als, ald, ev, menc, 1);
  edge_exp_k<<<EB, 256, 0, stream>>>(ei, menc, ev, csr_pos, evs, denom, 1);
  aggregate_k<4><<<N_NODES, 192, 0, stream>>>(h3, evs, denom, b2, rowstart,
                                              csr_src, out, 1, C2);
}

// Round 7
// 614.570 us; speedup vs baseline: 1.2002x; 1.0375x over previous
//
#include <hip/hip_runtime.h>
#include <hip/hip_bf16.h>
#include <math.h>

// ---------------- problem constants ----------------
#define N_NODES 10000
#define N_EDGES0 160000
#define E_TOT (N_EDGES0 + N_NODES)   // + self loops
#define H1 4
#define C1 512
#define F1 2048                      // H1*C1
#define IN_DIM 768
#define C2 768
#define NEG_SLOPE 0.2f

typedef _Float16 f16x8 __attribute__((ext_vector_type(8)));
typedef _Float16 f16x4 __attribute__((ext_vector_type(4)));
typedef float f32x4 __attribute__((ext_vector_type(4)));

typedef __attribute__((address_space(1))) const void* gas_ptr;
typedef __attribute__((address_space(3))) void* las_ptr;
static __device__ __forceinline__ void gload16(const void* g, void* l) {
  __builtin_amdgcn_global_load_lds((gas_ptr)g, (las_ptr)l, 16, 0, 0);
}

// Monotonic float<->unsigned encoding so atomicMax works for signed floats.
static __device__ __forceinline__ unsigned enc_f(float v) {
  unsigned u = __float_as_uint(v);
  return (u & 0x80000000u) ? ~u : (u | 0x80000000u);
}
static __device__ __forceinline__ float dec_f(unsigned u) {
  return (u & 0x80000000u) ? __uint_as_float(u ^ 0x80000000u)
                           : __uint_as_float(~u);
}

// edge e -> (src, dst); e >= N_EDGES0 are the implicit self-loops
static __device__ __forceinline__ void edge_sd(const int* __restrict__ ei, int e,
                                               int& s, int& d) {
  if (e < N_EDGES0) { s = ei[e]; d = ei[N_EDGES0 + e]; }
  else { s = e - N_EDGES0; d = s; }
}

// ---------------- W [K][N] fp32 -> W^T [N][K] f16 hi/lo ---------------------
__global__ void tsplit_k(const float* __restrict__ W, _Float16* __restrict__ hi,
                         _Float16* __restrict__ lo, int K, int N) {
  __shared__ float tile[32][33];
  const int nb = blockIdx.x * 32, kb = blockIdx.y * 32;
  const int tx = threadIdx.x, ty = threadIdx.y;  // 32 x 8
  for (int r = ty; r < 32; r += 8)
    tile[r][tx] = W[(size_t)(kb + r) * N + nb + tx];
  __syncthreads();
  for (int r = ty; r < 32; r += 8) {
    float v = tile[tx][r];  // = W[kb+tx][nb+r]
    _Float16 h = (_Float16)v;
    hi[(size_t)(nb + r) * K + kb + tx] = h;
    lo[(size_t)(nb + r) * K + kb + tx] = (_Float16)(v - (float)h);
  }
}

// ---- layer-1 attn vectors projected into x-space: ws[h,k] = sum_c W1[k,h*C1+c]*a[h,c]
__global__ void proj_attn_k(const float* __restrict__ W1,
                            const float* __restrict__ as1,
                            const float* __restrict__ ad1,
                            float* __restrict__ ws, float* __restrict__ wd) {
  int wv = (blockIdx.x * blockDim.x + threadIdx.x) >> 6;
  int lane = threadIdx.x & 63;
  if (wv >= H1 * IN_DIM) return;
  int h = wv / IN_DIM, k = wv - h * IN_DIM;
  const float* wrow = W1 + (size_t)k * F1 + h * C1;
  const float* sa = as1 + h * C1;
  const float* da = ad1 + h * C1;
  float ss = 0.f, sd = 0.f;
  for (int c = lane; c < C1; c += 64) {
    float v = wrow[c];
    ss = fmaf(v, sa[c], ss);
    sd = fmaf(v, da[c], sd);
  }
#pragma unroll
  for (int o = 32; o; o >>= 1) { ss += __shfl_xor(ss, o); sd += __shfl_xor(sd, o); }
  if (lane == 0) { ws[(size_t)h * IN_DIM + k] = ss; wd[(size_t)h * IN_DIM + k] = sd; }
}

// ---- layer-1 logits from raw x: als[n,h] = x[n,:] . ws[h,:]
__global__ void logits1_k(const float* __restrict__ x,
                          const float* __restrict__ ws, const float* __restrict__ wd,
                          float* __restrict__ als, float* __restrict__ ald) {
  int n = (blockIdx.x * blockDim.x + threadIdx.x) >> 6;
  int lane = threadIdx.x & 63;
  if (n >= N_NODES) return;
  const float* xp = x + (size_t)n * IN_DIM;
  float ss[H1] = {0.f, 0.f, 0.f, 0.f}, sd[H1] = {0.f, 0.f, 0.f, 0.f};
  for (int k = lane; k < IN_DIM; k += 64) {
    float xv = xp[k];
#pragma unroll
    for (int h = 0; h < H1; h++) {
      ss[h] = fmaf(xv, ws[h * IN_DIM + k], ss[h]);
      sd[h] = fmaf(xv, wd[h * IN_DIM + k], sd[h]);
    }
  }
#pragma unroll
  for (int h = 0; h < H1; h++)
#pragma unroll
    for (int o = 32; o; o >>= 1) { ss[h] += __shfl_xor(ss[h], o); sd[h] += __shfl_xor(sd[h], o); }
  if (lane == 0) {
#pragma unroll
    for (int h = 0; h < H1; h++) {
      als[(size_t)n * H1 + h] = ss[h];
      ald[(size_t)n * H1 + h] = sd[h];
    }
  }
}

// ---------------- split-f16 MFMA GEMM: C[M,N] = A[M,K] @ Bt[N,K]^T ----------
// BK=64 (12/32 K-steps -> half the barrier drains of BK=32).
// LDS layout [128 rows][64 f16] = 128B rows. Naive layout would be a 16-way
// bank conflict on frag reads; swizzle: LDS granule (row, g') holds global
// granule (row, (g'-row)&7).  Stage: linear LDS dest + inverse-swizzled
// GLOBAL source, g_src = ((lane&7)-(lane>>3))&7 (rule 21: both sides, same
// involution).  Read: g' = (kk*4 + lg + (lr&7)) & 7  -> 8 cols x 2-way (free).
// XCD remap (m204 bijective): each XCD gets contiguous block-rows -> A-panel
// L2 locality.
template <bool SPLITOUT>
__global__ __launch_bounds__(256) void gemm_sf16(
    const _Float16* __restrict__ Ahi, const _Float16* __restrict__ Alo,
    const _Float16* __restrict__ Bhi, const _Float16* __restrict__ Blo,
    int M, int N, int K, int lda, int nch, int nbx, int nwg,
    float* __restrict__ C, const float* __restrict__ bias,
    _Float16* __restrict__ ohi, _Float16* __restrict__ olo,
    const float* __restrict__ asrc, const float* __restrict__ adst,
    float* __restrict__ als, float* __restrict__ ald, int Hh, int Cdim) {
  __shared__ _Float16 sAh[128 * 64];
  __shared__ _Float16 sAl[128 * 64];
  __shared__ _Float16 sBh[128 * 64];
  __shared__ _Float16 sBl[128 * 64];

  // bijective XCD-chunked remap (nwg need not be %8)
  const int orig = blockIdx.x;
  const int q = nwg >> 3, rr = nwg & 7;
  const int xcd = orig & 7, pos = orig >> 3;
  const int wgid = (xcd < rr ? xcd * (q + 1) : rr * (q + 1) + (xcd - rr) * q) + pos;
  const int bx = wgid % nbx, by = wgid / nbx;
  const int m0 = by * 128, n0 = bx * 128;

  const int t = threadIdx.x;
  const int w = t >> 6, lane = t & 63;
  const size_t hofs = (size_t)(n0 / nch) * K;

  // staging: chunk i covers LDS rows [i*32 + w*8, +8), granule = lane&7
  const int gsrc = ((lane & 7) - (lane >> 3)) & 7;   // inverse-swizzled source granule
  const int ru = w * 8 + (lane >> 3);                // row-within-32 offset
  size_t gA[4], gB[4];
#pragma unroll
  for (int i = 0; i < 4; i++) {
    const int ra = min(m0 + i * 32 + ru, M - 1);
    gA[i] = (size_t)ra * lda + hofs + gsrc * 8;
    gB[i] = (size_t)(n0 + i * 32 + ru) * K + gsrc * 8;
  }

  const int wr = w >> 1, wc = w & 1;
  const int lr = lane & 15, lg = lane >> 4;

  f32x4 acc[4][4];
#pragma unroll
  for (int i = 0; i < 4; i++)
#pragma unroll
    for (int j = 0; j < 4; j++) acc[i][j] = (f32x4)(0.f);

  for (int k0 = 0; k0 < K; k0 += 64) {
    __syncthreads();  // previous iter's ds_reads done before overwrite
#pragma unroll
    for (int i = 0; i < 4; i++) {
      const int lofs = w * 1024 + i * 4096;
      gload16(Ahi + gA[i] + k0, (char*)sAh + lofs);
      gload16(Alo + gA[i] + k0, (char*)sAl + lofs);
      gload16(Bhi + gB[i] + k0, (char*)sBh + lofs);
      gload16(Blo + gB[i] + k0, (char*)sBl + lofs);
    }
    __syncthreads();  // barrier drains vmcnt -> tiles ready

#pragma unroll
    for (int kk = 0; kk < 2; kk++) {
      const int ga = ((kk * 4 + lg + (lr & 7)) & 7) * 8;  // swizzled granule (elems)
      f16x8 ah[4], al[4], bh[4], bl[4];
#pragma unroll
      for (int i = 0; i < 4; i++) {
        const int ao = (wr * 64 + i * 16 + lr) * 64 + ga;
        const int bo = (wc * 64 + i * 16 + lr) * 64 + ga;
        ah[i] = *(const f16x8*)&sAh[ao];
        al[i] = *(const f16x8*)&sAl[ao];
        bh[i] = *(const f16x8*)&sBh[bo];
        bl[i] = *(const f16x8*)&sBl[bo];
      }
#pragma unroll
      for (int i = 0; i < 4; i++)
#pragma unroll
        for (int j = 0; j < 4; j++) {
          acc[i][j] = __builtin_amdgcn_mfma_f32_16x16x32_f16(ah[i], bh[j], acc[i][j], 0, 0, 0);
          acc[i][j] = __builtin_amdgcn_mfma_f32_16x16x32_f16(ah[i], bl[j], acc[i][j], 0, 0, 0);
          acc[i][j] = __builtin_amdgcn_mfma_f32_16x16x32_f16(al[i], bh[j], acc[i][j], 0, 0, 0);
        }
    }
  }

  // C/D layout: col = lane&15, row = (lane>>4)*4 + reg  [m89/m91 verified]
  if constexpr (SPLITOUT) {
    // bias + ELU + f16 hi/lo split (feeds next GEMM's A)
#pragma unroll
    for (int j = 0; j < 4; j++) {
      const int col = n0 + wc * 64 + j * 16 + lr;
      const float bv = bias[col];
#pragma unroll
      for (int i = 0; i < 4; i++) {
        const int rbase = m0 + wr * 64 + i * 16 + lg * 4;
#pragma unroll
        for (int r = 0; r < 4; r++) {
          const int row = rbase + r;
          if (row < M) {
            float o = acc[i][j][r] + bv;
            o = o > 0.f ? o : expm1f(o);
            _Float16 hv = (_Float16)o;
            ohi[(size_t)row * N + col] = hv;
            olo[(size_t)row * N + col] = (_Float16)(o - (float)hv);
          }
        }
      }
    }
  } else {
#pragma unroll
    for (int i = 0; i < 4; i++)
#pragma unroll
      for (int j = 0; j < 4; j++) {
        const int col = n0 + wc * 64 + j * 16 + lr;
        const int rbase = m0 + wr * 64 + i * 16 + lg * 4;
#pragma unroll
        for (int r = 0; r < 4; r++) {
          int row = rbase + r;
          if (row < M) C[(size_t)row * N + col] = acc[i][j][r];
        }
      }

    // fused attention logits (128-col tile lies in one head)
    const int head = n0 / Cdim;
    const int cbase = n0 - head * Cdim + wc * 64 + lr;
    float asv[4], adv[4];
#pragma unroll
    for (int j = 0; j < 4; j++) {
      asv[j] = asrc[(size_t)head * Cdim + cbase + j * 16];
      adv[j] = adst[(size_t)head * Cdim + cbase + j * 16];
    }
#pragma unroll
    for (int i = 0; i < 4; i++) {
      const int rbase = m0 + wr * 64 + i * 16 + lg * 4;
#pragma unroll
      for (int r = 0; r < 4; r++) {
        float ss = 0.f, sd = 0.f;
#pragma unroll
        for (int j = 0; j < 4; j++) {
          float v = acc[i][j][r];
          ss = fmaf(v, asv[j], ss);
          sd = fmaf(v, adv[j], sd);
        }
#pragma unroll
        for (int o = 8; o; o >>= 1) {
          ss += __shfl_xor(ss, o);
          sd += __shfl_xor(sd, o);
        }
        if (lr == 0 && rbase + r < M) {
          atomicAdd(&als[(size_t)(rbase + r) * Hh + head], ss);
          atomicAdd(&ald[(size_t)(rbase + r) * Hh + head], sd);
        }
      }
    }
  }
}

// ---------------- edge softmax passes ----------------
__global__ void edge_max_k(const int* __restrict__ ei,
                           const float* __restrict__ als,
                           const float* __restrict__ ald,
                           float* __restrict__ ev, unsigned* __restrict__ menc,
                           int Hh) {
  int idx = blockIdx.x * blockDim.x + threadIdx.x;
  if (idx >= E_TOT * Hh) return;
  int e = idx / Hh, hh = idx - e * Hh;
  int s, d; edge_sd(ei, e, s, d);
  float x = als[s * Hh + hh] + ald[d * Hh + hh];
  float v = x > 0.f ? x : NEG_SLOPE * x;   // leaky_relu
  ev[idx] = v;
  atomicMax(&menc[d * Hh + hh], enc_f(v));
}

// writes exp values in CSR (dst-sorted) order -> contiguous reads in aggregation
__global__ void edge_exp_k(const int* __restrict__ ei,
                           const unsigned* __restrict__ menc,
                           const float* __restrict__ ev,
                           const int* __restrict__ csr_pos,
                           float* __restrict__ evs, float* __restrict__ denom,
                           int Hh) {
  int idx = blockIdx.x * blockDim.x + threadIdx.x;
  if (idx >= E_TOT * Hh) return;
  int e = idx / Hh, hh = idx - e * Hh;
  int s, d; edge_sd(ei, e, s, d);
  float m = dec_f(menc[d * Hh + hh]);
  float ex = expf(ev[idx] - m);
  evs[(size_t)csr_pos[e] * Hh + hh] = ex;
  atomicAdd(&denom[d * Hh + hh], ex);
}

// ---------------- CSR build (dst-sorted) ----------------
__global__ void hist_k(const int* __restrict__ ei, int* __restrict__ count) {
  int e = blockIdx.x * blockDim.x + threadIdx.x;
  if (e >= E_TOT) return;
  int s, d; edge_sd(ei, e, s, d);
  atomicAdd(&count[d], 1);
}

__global__ __launch_bounds__(1024) void scan_k(const int* __restrict__ count,
                                               int* __restrict__ rowstart,
                                               int N, int total) {
  __shared__ int sums[1024];
  __shared__ int carry_s;
  int t = threadIdx.x;
  if (t == 0) carry_s = 0;
  __syncthreads();
  for (int base = 0; base < N; base += 1024) {
    int i = base + t;
    int c = (i < N) ? count[i] : 0;
    sums[t] = c;
    __syncthreads();
    for (int off = 1; off < 1024; off <<= 1) {
      int v = (t >= off) ? sums[t - off] : 0;
      __syncthreads();
      sums[t] += v;
      __syncthreads();
    }
    int carry = carry_s;
    if (i < N) rowstart[i] = carry + sums[t] - c;  // exclusive
    __syncthreads();
    if (t == 1023) carry_s = carry + sums[1023];
    __syncthreads();
  }
  if (t == 0) rowstart[N] = total;
}

__global__ void scatter_k(const int* __restrict__ ei,
                          const int* __restrict__ rowstart,
                          int* __restrict__ cursor,
                          int* __restrict__ csr_src, int* __restrict__ csr_pos) {
  int e = blockIdx.x * blockDim.x + threadIdx.x;
  if (e >= E_TOT) return;
  int s, d; edge_sd(ei, e, s, d);
  int pos = rowstart[d] + atomicAdd(&cursor[d], 1);
  csr_src[pos] = s;
  csr_pos[e] = pos;   // inverse permutation (edge -> CSR slot)
}

// ---- layer-1 aggregation of RAW x (per head): xa[n,h,:] = sum alpha[e,h] x[s,:]
// writes f16 hi/lo [N][H1][IN_DIM] (GEMM1 A, lda = H1*IN_DIM)
__global__ __launch_bounds__(192) void aggregate_x_k(
    const float* __restrict__ x, const float* __restrict__ evs,
    const float* __restrict__ denom, const int* __restrict__ rowstart,
    const int* __restrict__ csr_src,
    _Float16* __restrict__ ohi, _Float16* __restrict__ olo) {
  const int n = blockIdx.x;
  const int f0 = threadIdx.x * 4;  // < 768
  float inv[H1];
#pragma unroll
  for (int h = 0; h < H1; h++) inv[h] = 1.f / (denom[n * H1 + h] + 1e-16f);
  float acc[H1][4];
#pragma unroll
  for (int h = 0; h < H1; h++)
#pragma unroll
    for (int q = 0; q < 4; q++) acc[h][q] = 0.f;

  const int j0 = rowstart[n], j1 = rowstart[n + 1];
  int j = j0;
  for (; j + 4 <= j1; j += 4) {
    int sidx[4];
    float4 wv[4], xv[4];
#pragma unroll
    for (int u = 0; u < 4; u++) sidx[u] = csr_src[j + u];
#pragma unroll
    for (int u = 0; u < 4; u++) wv[u] = *(const float4*)&evs[(size_t)(j + u) * H1];
#pragma unroll
    for (int u = 0; u < 4; u++)
      xv[u] = *(const float4*)(x + (size_t)sidx[u] * IN_DIM + f0);
#pragma unroll
    for (int u = 0; u < 4; u++) {
      const float* pw = (const float*)&wv[u];
#pragma unroll
      for (int h = 0; h < H1; h++) {
        acc[h][0] = fmaf(pw[h], xv[u].x, acc[h][0]);
        acc[h][1] = fmaf(pw[h], xv[u].y, acc[h][1]);
        acc[h][2] = fmaf(pw[h], xv[u].z, acc[h][2]);
        acc[h][3] = fmaf(pw[h], xv[u].w, acc[h][3]);
      }
    }
  }
  for (; j < j1; j++) {
    int s = csr_src[j];
    float4 wv = *(const float4*)&evs[(size_t)j * H1];
    float4 xv = *(const float4*)(x + (size_t)s * IN_DIM + f0);
    const float* pw = (const float*)&wv;
#pragma unroll
    for (int h = 0; h < H1; h++) {
      acc[h][0] = fmaf(pw[h], xv.x, acc[h][0]);
      acc[h][1] = fmaf(pw[h], xv.y, acc[h][1]);
      acc[h][2] = fmaf(pw[h], xv.z, acc[h][2]);
      acc[h][3] = fmaf(pw[h], xv.w, acc[h][3]);
    }
  }

#pragma unroll
  for (int h = 0; h < H1; h++) {
    f16x4 h4, l4;
#pragma unroll
    for (int q = 0; q < 4; q++) {
      float o = acc[h][q] * inv[h];
      _Float16 hv = (_Float16)o;
      h4[q] = hv;
      l4[q] = (_Float16)(o - (float)hv);
    }
    *(f16x4*)&ohi[(size_t)n * (H1 * IN_DIM) + h * IN_DIM + f0] = h4;
    *(f16x4*)&olo[(size_t)n * (H1 * IN_DIM) + h * IN_DIM + f0] = l4;
  }
}

// ---------------- layer-2 aggregation: out[n,:] = (sum ev*h3[src,:])/denom + b ----
template <int FT>
__global__ __launch_bounds__(256) void aggregate_k(
    const float* __restrict__ hsrc, const float* __restrict__ evs,
    const float* __restrict__ denom, const float* __restrict__ bias,
    const int* __restrict__ rowstart, const int* __restrict__ csr_src,
    float* __restrict__ out, int Hh, int C) {
  const int n = blockIdx.x;
  const int t = threadIdx.x;
  const int F = Hh * C;
  const int f0 = t * FT;
  const int hh = f0 / C;
  const float inv = 1.f / (denom[n * Hh + hh] + 1e-16f);
  float acc[FT];
#pragma unroll
  for (int i = 0; i < FT; i++) acc[i] = 0.f;
  const int j0 = rowstart[n], j1 = rowstart[n + 1];

  constexpr int UN = 8;
  int j = j0;
  for (; j + UN <= j1; j += UN) {
    int   sidx[UN];
    float wv[UN];
#pragma unroll
    for (int u = 0; u < UN; u++) sidx[u] = csr_src[j + u];
#pragma unroll
    for (int u = 0; u < UN; u++) wv[u] = evs[(size_t)(j + u) * Hh + hh];
    float4 va[UN][FT / 4];
#pragma unroll
    for (int u = 0; u < UN; u++) {
      const float* hp = hsrc + (size_t)sidx[u] * F + f0;
#pragma unroll
      for (int q = 0; q < FT / 4; q++) va[u][q] = *(const float4*)(hp + q * 4);
    }
#pragma unroll
    for (int u = 0; u < UN; u++)
#pragma unroll
      for (int q = 0; q < FT / 4; q++) {
        acc[q * 4 + 0] = fmaf(wv[u], va[u][q].x, acc[q * 4 + 0]);
        acc[q * 4 + 1] = fmaf(wv[u], va[u][q].y, acc[q * 4 + 1]);
        acc[q * 4 + 2] = fmaf(wv[u], va[u][q].z, acc[q * 4 + 2]);
        acc[q * 4 + 3] = fmaf(wv[u], va[u][q].w, acc[q * 4 + 3]);
      }
  }
  for (; j < j1; j++) {
    int s = csr_src[j];
    float wgt = evs[(size_t)j * Hh + hh];
    const float* hp = hsrc + (size_t)s * F + f0;
#pragma unroll
    for (int q = 0; q < FT / 4; q++) {
      float4 v = *(const float4*)(hp + q * 4);
      acc[q * 4 + 0] = fmaf(wgt, v.x, acc[q * 4 + 0]);
      acc[q * 4 + 1] = fmaf(wgt, v.y, acc[q * 4 + 1]);
      acc[q * 4 + 2] = fmaf(wgt, v.z, acc[q * 4 + 2]);
      acc[q * 4 + 3] = fmaf(wgt, v.w, acc[q * 4 + 3]);
    }
  }
#pragma unroll
  for (int i = 0; i < FT; i++)
    out[(size_t)n * F + f0 + i] = acc[i] * inv + bias[f0 + i];
}

// ---------------- launch ----------------
extern "C" void kernel_launch(void* const* d_in, const int* in_sizes, int n_in,
                              void* d_out, int out_size, void* d_ws, size_t ws_size,
                              hipStream_t stream) {
  const float* x   = (const float*)d_in[0];
  const int*   ei  = (const int*)d_in[1];   // [2, 160000]; JAX x64 off -> int32
  const float* W1  = (const float*)d_in[2];
  const float* as1 = (const float*)d_in[3];
  const float* ad1 = (const float*)d_in[4];
  const float* b1  = (const float*)d_in[5];
  const float* W2  = (const float*)d_in[6];
  const float* as2 = (const float*)d_in[7];
  const float* ad2 = (const float*)d_in[8];
  const float* b2  = (const float*)d_in[9];
  float* out = (float*)d_out;

  char* p = (char*)d_ws;
  auto alloc = [&](size_t bytes) {
    char* r = p;
    p += (bytes + 255) & ~(size_t)255;
    return r;
  };
  _Float16* xahi  = (_Float16*)alloc((size_t)N_NODES * H1 * IN_DIM * 2);  // 61.4 MB
  _Float16* xalo  = (_Float16*)alloc((size_t)N_NODES * H1 * IN_DIM * 2);
  _Float16* W1hi  = (_Float16*)alloc((size_t)IN_DIM * F1 * 2);            // [F1][IN_DIM]
  _Float16* W1lo  = (_Float16*)alloc((size_t)IN_DIM * F1 * 2);
  _Float16* W2hi  = (_Float16*)alloc((size_t)F1 * C2 * 2);                // [C2][F1]
  _Float16* W2lo  = (_Float16*)alloc((size_t)F1 * C2 * 2);
  _Float16* h2hi  = (_Float16*)alloc((size_t)N_NODES * F1 * 2);           // 41 MB
  _Float16* h2lo  = (_Float16*)alloc((size_t)N_NODES * F1 * 2);
  float*    ws1   = (float*)alloc((size_t)H1 * IN_DIM * 4);
  float*    wd1   = (float*)alloc((size_t)H1 * IN_DIM * 4);
  float*    als   = (float*)alloc((size_t)N_NODES * H1 * 4);
  float*    ald   = (float*)alloc((size_t)N_NODES * H1 * 4);
  unsigned* menc  = (unsigned*)alloc((size_t)N_NODES * H1 * 4);
  float*    denom = (float*)alloc((size_t)N_NODES * H1 * 4);
  float*    ev    = (float*)alloc((size_t)E_TOT * H1 * 4);
  float*    evs   = (float*)alloc((size_t)E_TOT * H1 * 4);
  int*      count    = (int*)alloc((size_t)N_NODES * 4);
  int*      rowstart = (int*)alloc((size_t)(N_NODES + 1) * 4);
  int*      cursor   = (int*)alloc((size_t)N_NODES * 4);
  int*      csr_src  = (int*)alloc((size_t)E_TOT * 4);
  int*      csr_pos  = (int*)alloc((size_t)E_TOT * 4);
  float*    h3 = (float*)xahi;  // xa dead after GEMM1; alias (30.7 <= 61.4 MB)

  const int EB = (E_TOT + 255) / 256;
  const int MT = (N_NODES + 127) / 128;   // 79 M-tiles

  // CSR by destination (same graph both layers)
  hipMemsetAsync(count, 0, (size_t)N_NODES * 4, stream);
  hipMemsetAsync(cursor, 0, (size_t)N_NODES * 4, stream);
  hist_k<<<EB, 256, 0, stream>>>(ei, count);
  scan_k<<<1, 1024, 0, stream>>>(count, rowstart, N_NODES, E_TOT);
  scatter_k<<<EB, 256, 0, stream>>>(ei, rowstart, cursor, csr_src, csr_pos);

  // weight conversions + projected attn vectors
  tsplit_k<<<dim3(F1 / 32, IN_DIM / 32), dim3(32, 8), 0, stream>>>(W1, W1hi, W1lo,
                                                                   IN_DIM, F1);
  tsplit_k<<<dim3(C2 / 32, F1 / 32), dim3(32, 8), 0, stream>>>(W2, W2hi, W2lo,
                                                               F1, C2);
  proj_attn_k<<<(H1 * IN_DIM * 64) / 256, 256, 0, stream>>>(W1, as1, ad1, ws1, wd1);

  // ---- layer 1 (aggregate-then-project) ----
  logits1_k<<<(N_NODES * 64 + 255) / 256, 256, 0, stream>>>(x, ws1, wd1, als, ald);
  hipMemsetAsync(menc, 0, (size_t)N_NODES * H1 * 4, stream);
  hipMemsetAsync(denom, 0, (size_t)N_NODES * H1 * 4, stream);
  edge_max_k<<<(E_TOT * H1 + 255) / 256, 256, 0, stream>>>(ei, als, ald, ev, menc, H1);
  edge_exp_k<<<(E_TOT * H1 + 255) / 256, 256, 0, stream>>>(ei, menc, ev, csr_pos,
                                                           evs, denom, H1);
  aggregate_x_k<<<N_NODES, 192, 0, stream>>>(x, evs, denom, rowstart, csr_src,
                                             xahi, xalo);
  // h2 = ELU(xa @ W1 + b1), written as f16 hi/lo
  {
    const int nbx = F1 / 128, nwg = nbx * MT;
    gemm_sf16<true><<<nwg, 256, 0, stream>>>(
        xahi, xalo, W1hi, W1lo, N_NODES, F1, IN_DIM, H1 * IN_DIM, C1, nbx, nwg,
        nullptr, b1, h2hi, h2lo, nullptr, nullptr, nullptr, nullptr, 0, C1);
  }

  // ---- layer 2 (project-then-aggregate, fused logits) ----
  hipMemsetAsync(als, 0, (size_t)N_NODES * 4, stream);
  hipMemsetAsync(ald, 0, (size_t)N_NODES * 4, stream);
  {
    const int nbx = C2 / 128, nwg = nbx * MT;
    gemm_sf16<false><<<nwg, 256, 0, stream>>>(
        h2hi, h2lo, W2hi, W2lo, N_NODES, C2, F1, F1, 1 << 30, nbx, nwg,
        h3, nullptr, nullptr, nullptr, as2, ad2, als, ald, 1, C2);
  }
  hipMemsetAsync(menc, 0, (size_t)N_NODES * 4, stream);
  hipMemsetAsync(denom, 0, (size_t)N_NODES * 4, stream);
  edge_max_k<<<EB, 256, 0, stream>>>(ei, als, ald, ev, menc, 1);
  edge_exp_k<<<EB, 256, 0, stream>>>(ei, menc, ev, csr_pos, evs, denom, 1);
  aggregate_k<4><<<N_NODES, 192, 0, stream>>>(h3, evs, denom, b2, rowstart,
                                              csr_src, out, 1, C2);
}